// Round 2
// baseline (12711.172 us; speedup 1.0000x reference)
//
#include <hip/hip_runtime.h>

#define N_NODES 100000
#define NE      1600000
#define C       128

// ---------------- degree accumulation: deg[col[e]] += ew[e] ----------------
__global__ __launch_bounds__(256) void deg_kernel(const int* __restrict__ col,
                                                  const float* __restrict__ ew,
                                                  float* __restrict__ deg) {
    int e = blockIdx.x * 256 + threadIdx.x;
    if (e < NE) atomicAdd(&deg[col[e]], ew[e]);
}

// ---------------- dinv[i] = 1/sqrt(deg[i] + 1.0)  (self-loop weight 1) -----
__global__ __launch_bounds__(256) void dinv_kernel(float* __restrict__ deg) {
    int i = blockIdx.x * 256 + threadIdx.x;
    if (i < N_NODES) {
        float d = deg[i] + 1.0f;          // always > 0
        deg[i] = 1.0f / sqrtf(d);
    }
}

// ---------------- norm[e] = dinv[row]*ew*dinv[col] -------------------------
__global__ __launch_bounds__(256) void norm_kernel(const int* __restrict__ row,
                                                   const int* __restrict__ col,
                                                   const float* __restrict__ ew,
                                                   const float* __restrict__ dinv,
                                                   float* __restrict__ norm) {
    int e = blockIdx.x * 256 + threadIdx.x;
    if (e < NE) norm[e] = dinv[row[e]] * ew[e] * dinv[col[e]];
}

// ---------------- GEMM: Y[n][128] = X[n][128] @ W[128][128] ----------------
// 64 rows x 64 cols per block (grid.y = 2 covers 128 cols), 256 threads,
// 4x4 microtile per thread. X tile + transposed-W tile staged in LDS,
// leading dim padded to 132 (16B-aligned, breaks power-of-2 bank stride).
__global__ __launch_bounds__(256) void gemm128(const float* __restrict__ X,
                                               const float* __restrict__ W,
                                               float* __restrict__ Y, int n) {
    __shared__ float sX[64 * 132];
    __shared__ float sW[64 * 132];   // sW[j][k] = W[k][col0+j]
    const int row0 = blockIdx.x * 64;
    const int col0 = blockIdx.y * 64;
    const int tid  = threadIdx.x;

    // stage X tile: 64 rows x 32 float4
    for (int i = tid; i < 64 * 32; i += 256) {
        int r = i >> 5, kq = i & 31;
        int gr = row0 + r;
        float4 v = make_float4(0.f, 0.f, 0.f, 0.f);
        if (gr < n) v = ((const float4*)X)[gr * 32 + kq];
        ((float4*)(sX + r * 132))[kq] = v;
    }
    // stage W tile transposed (coalesced global read over j)
    for (int i = tid; i < 128 * 64; i += 256) {
        int k = i >> 6, j = i & 63;
        sW[j * 132 + k] = W[k * 128 + col0 + j];
    }
    __syncthreads();

    const int ty = tid >> 4, tx = tid & 15;
    const float* xb = sX + (ty * 4) * 132;
    const float* wb = sW + (tx * 4) * 132;
    float acc[4][4] = {};
#pragma unroll
    for (int k = 0; k < 128; k += 4) {
        float4 xv[4], wv[4];
#pragma unroll
        for (int r = 0; r < 4; r++) xv[r] = *(const float4*)(xb + r * 132 + k);
#pragma unroll
        for (int c = 0; c < 4; c++) wv[c] = *(const float4*)(wb + c * 132 + k);
#pragma unroll
        for (int r = 0; r < 4; r++)
#pragma unroll
            for (int c = 0; c < 4; c++)
                acc[r][c] += xv[r].x * wv[c].x + xv[r].y * wv[c].y +
                             xv[r].z * wv[c].z + xv[r].w * wv[c].w;
    }
#pragma unroll
    for (int r = 0; r < 4; r++) {
        int gr = row0 + ty * 4 + r;
        if (gr < n) {
            float4 o = make_float4(acc[r][0], acc[r][1], acc[r][2], acc[r][3]);
            *(float4*)&Y[gr * 128 + col0 + tx * 4] = o;
        }
    }
}

// ---------------- edge scatter: out[col] += norm * xw[row] -----------------
// 32 lanes per edge, each lane handles 4 cols (float4 gather, 4 atomics).
__global__ __launch_bounds__(256) void scatter_edges(const int* __restrict__ row,
                                                     const int* __restrict__ col,
                                                     const float* __restrict__ norm,
                                                     const float* __restrict__ xw,
                                                     float* __restrict__ out) {
    long long idx = (long long)blockIdx.x * 256 + threadIdx.x;
    int e = (int)(idx >> 5);
    int lane = (int)(idx & 31);
    if (e >= NE) return;
    int r = row[e];
    int c = col[e];
    float w = norm[e];
    float4 v = ((const float4*)xw)[r * 32 + lane];
    float* dst = out + (long long)c * 128 + lane * 4;
    atomicAdd(dst + 0, w * v.x);
    atomicAdd(dst + 1, w * v.y);
    atomicAdd(dst + 2, w * v.z);
    atomicAdd(dst + 3, w * v.w);
}

// ------------- epilogue: h = relu(acc + dinv^2 * xw + b), in-place ok ------
__global__ __launch_bounds__(256) void bias_relu_selfloop(const float* __restrict__ acc,
                                                          const float* __restrict__ xw,
                                                          const float* __restrict__ dinv,
                                                          const float* __restrict__ b,
                                                          float* __restrict__ h) {
    int idx = blockIdx.x * 256 + threadIdx.x;   // over N*32 float4s
    if (idx >= N_NODES * 32) return;
    int nrow = idx >> 5, q = idx & 31;
    float d = dinv[nrow];
    float s = d * d;
    float4 a  = ((const float4*)acc)[idx];
    float4 x  = ((const float4*)xw)[idx];
    float4 bb = ((const float4*)b)[q];
    float4 r;
    r.x = fmaxf(fmaf(s, x.x, a.x) + bb.x, 0.f);
    r.y = fmaxf(fmaf(s, x.y, a.y) + bb.y, 0.f);
    r.z = fmaxf(fmaf(s, x.z, a.z) + bb.z, 0.f);
    r.w = fmaxf(fmaf(s, x.w, a.w) + bb.w, 0.f);
    ((float4*)h)[idx] = r;
}

// ------------- final: out[n] = h[n] . lin_w + lin_b ------------------------
// one 64-lane wave per node, 2 elements per lane, shuffle reduce.
__global__ __launch_bounds__(256) void final_dot(const float* __restrict__ h,
                                                 const float* __restrict__ lw,
                                                 const float* __restrict__ lb,
                                                 float* __restrict__ out) {
    int node = blockIdx.x * 4 + (threadIdx.x >> 6);
    int lane = threadIdx.x & 63;
    if (node >= N_NODES) return;
    float2 hv = ((const float2*)h)[node * 64 + lane];
    float2 wv = ((const float2*)lw)[lane];
    float p = hv.x * wv.x + hv.y * wv.y;
#pragma unroll
    for (int off = 32; off; off >>= 1) p += __shfl_down(p, off);
    if (lane == 0) out[node] = p + lb[0];
}

extern "C" void kernel_launch(void* const* d_in, const int* in_sizes, int n_in,
                              void* d_out, int out_size, void* d_ws, size_t ws_size,
                              hipStream_t stream) {
    const float* x   = (const float*)d_in[0];
    const int*   ei  = (const int*)d_in[1];   // int64 in reference -> int32 on device
    const float* ea  = (const float*)d_in[2];
    const float* W1  = (const float*)d_in[3];
    const float* b1  = (const float*)d_in[4];
    const float* W2  = (const float*)d_in[5];
    const float* b2  = (const float*)d_in[6];
    const float* W3  = (const float*)d_in[7];
    const float* b3  = (const float*)d_in[8];
    const float* lw  = (const float*)d_in[9];
    const float* lb  = (const float*)d_in[10];
    float*       out = (float*)d_out;

    const int* row = ei;        // edge_index[0]
    const int* col = ei + NE;   // edge_index[1]

    // workspace layout (all fp32), ~109 MB total:
    float* ws   = (float*)d_ws;
    float* dinv = ws;                                   // N      (deg, then dinv in-place)
    float* norm = dinv + N_NODES;                       // E
    float* bufA = norm + NE;                            // N*128  (xw)
    float* bufB = bufA + (size_t)N_NODES * C;           // N*128  (scatter acc, then h in-place)

    const int BS = 256;
    dim3 gGemm((N_NODES + 63) / 64, 2);
    int gEdge  = (NE + BS - 1) / BS;
    int gScat  = (int)(((long long)NE * 32 + BS - 1) / BS);
    int gNode  = (N_NODES + BS - 1) / BS;
    int gElem4 = (N_NODES * 32 + BS - 1) / BS;
    int gFinal = (N_NODES + 3) / 4;

    // ---- normalization ----
    hipMemsetAsync(dinv, 0, N_NODES * sizeof(float), stream);
    deg_kernel<<<gEdge, BS, 0, stream>>>(col, ea, dinv);
    dinv_kernel<<<gNode, BS, 0, stream>>>(dinv);
    norm_kernel<<<gEdge, BS, 0, stream>>>(row, col, ea, dinv, norm);

    // ---- layer 1 ----
    gemm128<<<gGemm, BS, 0, stream>>>(x, W1, bufA, N_NODES);
    hipMemsetAsync(bufB, 0, (size_t)N_NODES * C * sizeof(float), stream);
    scatter_edges<<<gScat, BS, 0, stream>>>(row, col, norm, bufA, bufB);
    bias_relu_selfloop<<<gElem4, BS, 0, stream>>>(bufB, bufA, dinv, b1, bufB);

    // ---- layer 2 ----
    gemm128<<<gGemm, BS, 0, stream>>>(bufB, W2, bufA, N_NODES);
    hipMemsetAsync(bufB, 0, (size_t)N_NODES * C * sizeof(float), stream);
    scatter_edges<<<gScat, BS, 0, stream>>>(row, col, norm, bufA, bufB);
    bias_relu_selfloop<<<gElem4, BS, 0, stream>>>(bufB, bufA, dinv, b2, bufB);

    // ---- layer 3 ----
    gemm128<<<gGemm, BS, 0, stream>>>(bufB, W3, bufA, N_NODES);
    hipMemsetAsync(bufB, 0, (size_t)N_NODES * C * sizeof(float), stream);
    scatter_edges<<<gScat, BS, 0, stream>>>(row, col, norm, bufA, bufB);
    bias_relu_selfloop<<<gElem4, BS, 0, stream>>>(bufB, bufA, dinv, b3, bufB);

    // ---- final linear ----
    final_dot<<<gFinal, BS, 0, stream>>>(bufB, lw, lb, out);
}

// Round 3
// 5238.899 us; speedup vs baseline: 2.4263x; 2.4263x over previous
//
#include <hip/hip_runtime.h>

#define N_NODES 100000
#define NE      1600000
#define C       128
#define SCAN_CHUNK 2048

// ---------------- degree accumulation: deg[col[e]] += ew[e] ----------------
__global__ __launch_bounds__(256) void deg_kernel(const int* __restrict__ col,
                                                  const float* __restrict__ ew,
                                                  float* __restrict__ deg) {
    int e = blockIdx.x * 256 + threadIdx.x;
    if (e < NE) atomicAdd(&deg[col[e]], ew[e]);
}

// ---------------- dinv[i] = 1/sqrt(deg[i] + 1.0)  (self-loop weight 1) -----
__global__ __launch_bounds__(256) void dinv_kernel(float* __restrict__ deg) {
    int i = blockIdx.x * 256 + threadIdx.x;
    if (i < N_NODES) {
        float d = deg[i] + 1.0f;          // always > 0
        deg[i] = 1.0f / sqrtf(d);
    }
}

// ---------------- CSR build: histogram of col ------------------------------
__global__ __launch_bounds__(256) void count_kernel(const int* __restrict__ col,
                                                    int* __restrict__ cnt) {
    int e = blockIdx.x * 256 + threadIdx.x;
    if (e < NE) atomicAdd(&cnt[col[e]], 1);
}

// ---- multi-block exclusive scan over cnt[] (in place), chunk = 2048 -------
__global__ __launch_bounds__(256) void scan1_kernel(int* __restrict__ data,
                                                    int* __restrict__ bsums, int n) {
    __shared__ int lds[256];
    const int chunk = blockIdx.x;
    const int base  = chunk * SCAN_CHUNK;
    const int t     = threadIdx.x;
    int v[8];
    const int idx0 = base + t * 8;
#pragma unroll
    for (int i = 0; i < 8; i++) v[i] = (idx0 + i < n) ? data[idx0 + i] : 0;
    int run = 0;
#pragma unroll
    for (int i = 0; i < 8; i++) { int tmp = v[i]; v[i] = run; run += tmp; }
    lds[t] = run;
    __syncthreads();
    // Hillis-Steele inclusive scan over 256 thread-sums
    for (int off = 1; off < 256; off <<= 1) {
        int x = (t >= off) ? lds[t - off] : 0;
        __syncthreads();
        lds[t] += x;
        __syncthreads();
    }
    int texcl = t ? lds[t - 1] : 0;
#pragma unroll
    for (int i = 0; i < 8; i++)
        if (idx0 + i < n) data[idx0 + i] = v[i] + texcl;
    if (t == 255) bsums[chunk] = lds[255];
}

__global__ void scan2_kernel(int* __restrict__ bsums, int nchunks) {
    if (blockIdx.x == 0 && threadIdx.x == 0) {
        int run = 0;
        for (int c = 0; c < nchunks; c++) { int t = bsums[c]; bsums[c] = run; run += t; }
    }
}

__global__ __launch_bounds__(256) void scan3_kernel(int* __restrict__ data,
                                                    const int* __restrict__ bsums, int n) {
    int i = blockIdx.x * 256 + threadIdx.x;
    if (i < n) data[i] += bsums[i / SCAN_CHUNK];
}

// ---- fill sorted edge arrays: srow[pos], snorm[pos]; cursor -> inclusive --
__global__ __launch_bounds__(256) void fill_kernel(const int* __restrict__ row,
                                                   const int* __restrict__ col,
                                                   const float* __restrict__ ew,
                                                   const float* __restrict__ dinv,
                                                   int* __restrict__ cursor,
                                                   int* __restrict__ srow,
                                                   float* __restrict__ snorm) {
    int e = blockIdx.x * 256 + threadIdx.x;
    if (e >= NE) return;
    int c = col[e], r = row[e];
    int pos = atomicAdd(&cursor[c], 1);
    srow[pos]  = r;
    snorm[pos] = dinv[r] * ew[e] * dinv[c];
}

// ---------------- GEMM: Y[n][128] = X[n][128] @ W[128][128] ----------------
__global__ __launch_bounds__(256) void gemm128(const float* __restrict__ X,
                                               const float* __restrict__ W,
                                               float* __restrict__ Y, int n) {
    __shared__ float sX[64 * 132];
    __shared__ float sW[64 * 132];   // sW[j][k] = W[k][col0+j]
    const int row0 = blockIdx.x * 64;
    const int col0 = blockIdx.y * 64;
    const int tid  = threadIdx.x;

    for (int i = tid; i < 64 * 32; i += 256) {
        int r = i >> 5, kq = i & 31;
        int gr = row0 + r;
        float4 v = make_float4(0.f, 0.f, 0.f, 0.f);
        if (gr < n) v = ((const float4*)X)[gr * 32 + kq];
        ((float4*)(sX + r * 132))[kq] = v;
    }
    for (int i = tid; i < 128 * 64; i += 256) {
        int k = i >> 6, j = i & 63;
        sW[j * 132 + k] = W[k * 128 + col0 + j];
    }
    __syncthreads();

    const int ty = tid >> 4, tx = tid & 15;
    const float* xb = sX + (ty * 4) * 132;
    const float* wb = sW + (tx * 4) * 132;
    float acc[4][4] = {};
#pragma unroll
    for (int k = 0; k < 128; k += 4) {
        float4 xv[4], wv[4];
#pragma unroll
        for (int r = 0; r < 4; r++) xv[r] = *(const float4*)(xb + r * 132 + k);
#pragma unroll
        for (int c = 0; c < 4; c++) wv[c] = *(const float4*)(wb + c * 132 + k);
#pragma unroll
        for (int r = 0; r < 4; r++)
#pragma unroll
            for (int c = 0; c < 4; c++)
                acc[r][c] += xv[r].x * wv[c].x + xv[r].y * wv[c].y +
                             xv[r].z * wv[c].z + xv[r].w * wv[c].w;
    }
#pragma unroll
    for (int r = 0; r < 4; r++) {
        int gr = row0 + ty * 4 + r;
        if (gr < n) {
            float4 o = make_float4(acc[r][0], acc[r][1], acc[r][2], acc[r][3]);
            *(float4*)&Y[gr * 128 + col0 + tx * 4] = o;
        }
    }
}

// -------- CSR gather + fused self-loop/bias/relu: atomic-free --------------
// 32 lanes per node (8 nodes per 256-thread block), float4 per lane.
__global__ __launch_bounds__(256) void gather_csr(const int* __restrict__ cursor,
                                                  const int* __restrict__ srow,
                                                  const float* __restrict__ snorm,
                                                  const float* __restrict__ xw,
                                                  const float* __restrict__ dinv,
                                                  const float* __restrict__ bias,
                                                  float* __restrict__ h) {
    int node = blockIdx.x * 8 + (threadIdx.x >> 5);
    int lane = threadIdx.x & 31;
    if (node >= N_NODES) return;
    int start = node ? cursor[node - 1] : 0;
    int end   = cursor[node];
    float d = dinv[node];
    float s = d * d;
    float4 v0 = ((const float4*)xw)[node * 32 + lane];
    float4 acc = make_float4(s * v0.x, s * v0.y, s * v0.z, s * v0.w);
    if (start < end) {
        int   r = srow[start];
        float w = snorm[start];
        for (int e = start + 1;; ++e) {
            float4 v = ((const float4*)xw)[(size_t)r * 32 + lane];
            bool more = (e < end);
            int rn = 0; float wn = 0.f;
            if (more) { rn = srow[e]; wn = snorm[e]; }
            acc.x += w * v.x; acc.y += w * v.y;
            acc.z += w * v.z; acc.w += w * v.w;
            if (!more) break;
            r = rn; w = wn;
        }
    }
    float4 bb = ((const float4*)bias)[lane];
    acc.x = fmaxf(acc.x + bb.x, 0.f);
    acc.y = fmaxf(acc.y + bb.y, 0.f);
    acc.z = fmaxf(acc.z + bb.z, 0.f);
    acc.w = fmaxf(acc.w + bb.w, 0.f);
    ((float4*)h)[node * 32 + lane] = acc;
}

// ------------- fallback: atomic scatter (only if ws too small) -------------
__global__ __launch_bounds__(256) void norm_kernel(const int* __restrict__ row,
                                                   const int* __restrict__ col,
                                                   const float* __restrict__ ew,
                                                   const float* __restrict__ dinv,
                                                   float* __restrict__ norm) {
    int e = blockIdx.x * 256 + threadIdx.x;
    if (e < NE) norm[e] = dinv[row[e]] * ew[e] * dinv[col[e]];
}

__global__ __launch_bounds__(256) void scatter_edges(const int* __restrict__ row,
                                                     const int* __restrict__ col,
                                                     const float* __restrict__ norm,
                                                     const float* __restrict__ xw,
                                                     float* __restrict__ out) {
    long long idx = (long long)blockIdx.x * 256 + threadIdx.x;
    int e = (int)(idx >> 5);
    int lane = (int)(idx & 31);
    if (e >= NE) return;
    int r = row[e];
    int c = col[e];
    float w = norm[e];
    float4 v = ((const float4*)xw)[r * 32 + lane];
    float* dst = out + (long long)c * 128 + lane * 4;
    atomicAdd(dst + 0, w * v.x);
    atomicAdd(dst + 1, w * v.y);
    atomicAdd(dst + 2, w * v.z);
    atomicAdd(dst + 3, w * v.w);
}

__global__ __launch_bounds__(256) void bias_relu_selfloop(const float* __restrict__ acc,
                                                          const float* __restrict__ xw,
                                                          const float* __restrict__ dinv,
                                                          const float* __restrict__ b,
                                                          float* __restrict__ h) {
    int idx = blockIdx.x * 256 + threadIdx.x;
    if (idx >= N_NODES * 32) return;
    int nrow = idx >> 5, q = idx & 31;
    float d = dinv[nrow];
    float s = d * d;
    float4 a  = ((const float4*)acc)[idx];
    float4 x  = ((const float4*)xw)[idx];
    float4 bb = ((const float4*)b)[q];
    float4 r;
    r.x = fmaxf(fmaf(s, x.x, a.x) + bb.x, 0.f);
    r.y = fmaxf(fmaf(s, x.y, a.y) + bb.y, 0.f);
    r.z = fmaxf(fmaf(s, x.z, a.z) + bb.z, 0.f);
    r.w = fmaxf(fmaf(s, x.w, a.w) + bb.w, 0.f);
    ((float4*)h)[idx] = r;
}

// ------------- final: out[n] = h[n] . lin_w + lin_b ------------------------
__global__ __launch_bounds__(256) void final_dot(const float* __restrict__ h,
                                                 const float* __restrict__ lw,
                                                 const float* __restrict__ lb,
                                                 float* __restrict__ out) {
    int node = blockIdx.x * 4 + (threadIdx.x >> 6);
    int lane = threadIdx.x & 63;
    if (node >= N_NODES) return;
    float2 hv = ((const float2*)h)[node * 64 + lane];
    float2 wv = ((const float2*)lw)[lane];
    float p = hv.x * wv.x + hv.y * wv.y;
#pragma unroll
    for (int off = 32; off; off >>= 1) p += __shfl_down(p, off);
    if (lane == 0) out[node] = p + lb[0];
}

extern "C" void kernel_launch(void* const* d_in, const int* in_sizes, int n_in,
                              void* d_out, int out_size, void* d_ws, size_t ws_size,
                              hipStream_t stream) {
    const float* x   = (const float*)d_in[0];
    const int*   ei  = (const int*)d_in[1];   // int64 in reference -> int32 on device
    const float* ea  = (const float*)d_in[2];
    const float* W1  = (const float*)d_in[3];
    const float* b1  = (const float*)d_in[4];
    const float* W2  = (const float*)d_in[5];
    const float* b2  = (const float*)d_in[6];
    const float* W3  = (const float*)d_in[7];
    const float* b3  = (const float*)d_in[8];
    const float* lw  = (const float*)d_in[9];
    const float* lb  = (const float*)d_in[10];
    float*       out = (float*)d_out;

    const int* row = ei;        // edge_index[0]
    const int* col = ei + NE;   // edge_index[1]

    const int BS = 256;
    dim3 gGemm((N_NODES + 63) / 64, 2);
    int gEdge   = (NE + BS - 1) / BS;
    int gNode   = (N_NODES + BS - 1) / BS;
    int gFinal  = (N_NODES + 3) / 4;
    int nchunks = (N_NODES + SCAN_CHUNK - 1) / SCAN_CHUNK;

    // CSR workspace layout (4-byte units):
    //   dinv[N] | cursor[N] | bsums[64] | srow[E] | snorm[E] | bufA[N*C] | bufB[N*C]
    size_t csr_units = (size_t)N_NODES * 2 + 64 + (size_t)NE * 2 + (size_t)N_NODES * C * 2;
    if (ws_size >= csr_units * 4) {
        float* ws     = (float*)d_ws;
        float* dinv   = ws;
        int*   cursor = (int*)(dinv + N_NODES);
        int*   bsums  = cursor + N_NODES;
        int*   srow   = bsums + 64;
        float* snorm  = (float*)(srow + NE);
        float* bufA   = snorm + NE;
        float* bufB   = bufA + (size_t)N_NODES * C;

        hipMemsetAsync(dinv, 0, N_NODES * sizeof(float), stream);
        hipMemsetAsync(cursor, 0, N_NODES * sizeof(int), stream);
        deg_kernel<<<gEdge, BS, 0, stream>>>(col, ea, dinv);
        dinv_kernel<<<gNode, BS, 0, stream>>>(dinv);

        // CSR build
        count_kernel<<<gEdge, BS, 0, stream>>>(col, cursor);
        scan1_kernel<<<nchunks, BS, 0, stream>>>(cursor, bsums, N_NODES);
        scan2_kernel<<<1, 64, 0, stream>>>(bsums, nchunks);
        scan3_kernel<<<gNode, BS, 0, stream>>>(cursor, bsums, N_NODES);
        fill_kernel<<<gEdge, BS, 0, stream>>>(row, col, ea, dinv, cursor, srow, snorm);

        int gGather = (N_NODES + 7) / 8;
        // layer 1
        gemm128<<<gGemm, BS, 0, stream>>>(x, W1, bufA, N_NODES);
        gather_csr<<<gGather, BS, 0, stream>>>(cursor, srow, snorm, bufA, dinv, b1, bufB);
        // layer 2
        gemm128<<<gGemm, BS, 0, stream>>>(bufB, W2, bufA, N_NODES);
        gather_csr<<<gGather, BS, 0, stream>>>(cursor, srow, snorm, bufA, dinv, b2, bufB);
        // layer 3
        gemm128<<<gGemm, BS, 0, stream>>>(bufB, W3, bufA, N_NODES);
        gather_csr<<<gGather, BS, 0, stream>>>(cursor, srow, snorm, bufA, dinv, b3, bufB);

        final_dot<<<gFinal, BS, 0, stream>>>(bufB, lw, lb, out);
    } else {
        // fallback: atomic scatter path (~109 MB)
        float* ws   = (float*)d_ws;
        float* dinv = ws;
        float* norm = dinv + N_NODES;
        float* bufA = norm + NE;
        float* bufB = bufA + (size_t)N_NODES * C;
        int gScat  = (int)(((long long)NE * 32 + BS - 1) / BS);
        int gElem4 = (N_NODES * 32 + BS - 1) / BS;

        hipMemsetAsync(dinv, 0, N_NODES * sizeof(float), stream);
        deg_kernel<<<gEdge, BS, 0, stream>>>(col, ea, dinv);
        dinv_kernel<<<gNode, BS, 0, stream>>>(dinv);
        norm_kernel<<<gEdge, BS, 0, stream>>>(row, col, ea, dinv, norm);

        gemm128<<<gGemm, BS, 0, stream>>>(x, W1, bufA, N_NODES);
        hipMemsetAsync(bufB, 0, (size_t)N_NODES * C * sizeof(float), stream);
        scatter_edges<<<gScat, BS, 0, stream>>>(row, col, norm, bufA, bufB);
        bias_relu_selfloop<<<gElem4, BS, 0, stream>>>(bufB, bufA, dinv, b1, bufB);

        gemm128<<<gGemm, BS, 0, stream>>>(bufB, W2, bufA, N_NODES);
        hipMemsetAsync(bufB, 0, (size_t)N_NODES * C * sizeof(float), stream);
        scatter_edges<<<gScat, BS, 0, stream>>>(row, col, norm, bufA, bufB);
        bias_relu_selfloop<<<gElem4, BS, 0, stream>>>(bufB, bufA, dinv, b2, bufB);

        gemm128<<<gGemm, BS, 0, stream>>>(bufB, W3, bufA, N_NODES);
        hipMemsetAsync(bufB, 0, (size_t)N_NODES * C * sizeof(float), stream);
        scatter_edges<<<gScat, BS, 0, stream>>>(row, col, norm, bufA, bufB);
        bias_relu_selfloop<<<gElem4, BS, 0, stream>>>(bufB, bufA, dinv, b3, bufB);

        final_dot<<<gFinal, BS, 0, stream>>>(bufB, lw, lb, out);
    }
}

// Round 4
// 991.342 us; speedup vs baseline: 12.8222x; 5.2847x over previous
//
#include <hip/hip_runtime.h>

#define N_NODES 100000
#define NE      1600000
#define C       128
#define SCAN_CHUNK 2048

// ---------------- degree accumulation: deg[col[e]] += ew[e] ----------------
__global__ __launch_bounds__(256) void deg_kernel(const int* __restrict__ col,
                                                  const float* __restrict__ ew,
                                                  float* __restrict__ deg) {
    int e = blockIdx.x * 256 + threadIdx.x;
    if (e < NE) atomicAdd(&deg[col[e]], ew[e]);
}

// ---------------- dinv[i] = 1/sqrt(deg[i] + 1.0)  (self-loop weight 1) -----
__global__ __launch_bounds__(256) void dinv_kernel(float* __restrict__ deg) {
    int i = blockIdx.x * 256 + threadIdx.x;
    if (i < N_NODES) {
        float d = deg[i] + 1.0f;          // always > 0
        deg[i] = 1.0f / sqrtf(d);
    }
}

// ---------------- CSR build: histogram of col ------------------------------
__global__ __launch_bounds__(256) void count_kernel(const int* __restrict__ col,
                                                    int* __restrict__ cnt) {
    int e = blockIdx.x * 256 + threadIdx.x;
    if (e < NE) atomicAdd(&cnt[col[e]], 1);
}

// ---- multi-block exclusive scan over cnt[] (in place), chunk = 2048 -------
__global__ __launch_bounds__(256) void scan1_kernel(int* __restrict__ data,
                                                    int* __restrict__ bsums, int n) {
    __shared__ int lds[256];
    const int chunk = blockIdx.x;
    const int base  = chunk * SCAN_CHUNK;
    const int t     = threadIdx.x;
    int v[8];
    const int idx0 = base + t * 8;
#pragma unroll
    for (int i = 0; i < 8; i++) v[i] = (idx0 + i < n) ? data[idx0 + i] : 0;
    int run = 0;
#pragma unroll
    for (int i = 0; i < 8; i++) { int tmp = v[i]; v[i] = run; run += tmp; }
    lds[t] = run;
    __syncthreads();
    // Hillis-Steele inclusive scan over 256 thread-sums
    for (int off = 1; off < 256; off <<= 1) {
        int x = (t >= off) ? lds[t - off] : 0;
        __syncthreads();
        lds[t] += x;
        __syncthreads();
    }
    int texcl = t ? lds[t - 1] : 0;
#pragma unroll
    for (int i = 0; i < 8; i++)
        if (idx0 + i < n) data[idx0 + i] = v[i] + texcl;
    if (t == 255) bsums[chunk] = lds[255];
}

__global__ void scan2_kernel(int* __restrict__ bsums, int nchunks) {
    if (blockIdx.x == 0 && threadIdx.x == 0) {
        int run = 0;
        for (int c = 0; c < nchunks; c++) { int t = bsums[c]; bsums[c] = run; run += t; }
    }
}

__global__ __launch_bounds__(256) void scan3_kernel(int* __restrict__ data,
                                                    const int* __restrict__ bsums, int n) {
    int i = blockIdx.x * 256 + threadIdx.x;
    if (i < n) data[i] += bsums[i / SCAN_CHUNK];
}

// ---- fill sorted edge arrays: srow[pos], snorm[pos]; cursor -> inclusive --
__global__ __launch_bounds__(256) void fill_kernel(const int* __restrict__ row,
                                                   const int* __restrict__ col,
                                                   const float* __restrict__ ew,
                                                   const float* __restrict__ dinv,
                                                   int* __restrict__ cursor,
                                                   int* __restrict__ srow,
                                                   float* __restrict__ snorm) {
    int e = blockIdx.x * 256 + threadIdx.x;
    if (e >= NE) return;
    int c = col[e], r = row[e];
    int pos = atomicAdd(&cursor[c], 1);
    srow[pos]  = r;
    snorm[pos] = dinv[r] * ew[e] * dinv[c];
}

// ---------------- GEMM: Y[n][128] = X[n][128] @ W[128][128] ----------------
// 64 rows x 64 cols per block, 256 threads, 4x4 microtile.
// k-loop unroll bounded to 2 to keep VGPR pressure low (R3: full unroll ->
// 256 VGPRs + 4.3 GB scratch spill traffic -> 1540 us/dispatch).
__global__ __launch_bounds__(256) void gemm128(const float* __restrict__ X,
                                               const float* __restrict__ W,
                                               float* __restrict__ Y, int n) {
    __shared__ float sX[64 * 132];
    __shared__ float sW[64 * 132];   // sW[j][k] = W[k][col0+j]
    const int row0 = blockIdx.x * 64;
    const int col0 = blockIdx.y * 64;
    const int tid  = threadIdx.x;

    for (int i = tid; i < 64 * 32; i += 256) {
        int r = i >> 5, kq = i & 31;
        int gr = row0 + r;
        float4 v = make_float4(0.f, 0.f, 0.f, 0.f);
        if (gr < n) v = ((const float4*)X)[gr * 32 + kq];
        ((float4*)(sX + r * 132))[kq] = v;
    }
    for (int i = tid; i < 128 * 64; i += 256) {
        int k = i >> 6, j = i & 63;
        sW[j * 132 + k] = W[k * 128 + col0 + j];
    }
    __syncthreads();

    const int ty = tid >> 4, tx = tid & 15;
    const float* xb = sX + (ty * 4) * 132;
    const float* wb = sW + (tx * 4) * 132;
    float acc[4][4] = {};
#pragma unroll 2
    for (int k = 0; k < 128; k += 4) {
        float4 x0 = *(const float4*)(xb + k);
        float4 x1 = *(const float4*)(xb + 132 + k);
        float4 x2 = *(const float4*)(xb + 264 + k);
        float4 x3 = *(const float4*)(xb + 396 + k);
#pragma unroll
        for (int c = 0; c < 4; c++) {
            float4 wv = *(const float4*)(wb + c * 132 + k);
            acc[0][c] += x0.x * wv.x + x0.y * wv.y + x0.z * wv.z + x0.w * wv.w;
            acc[1][c] += x1.x * wv.x + x1.y * wv.y + x1.z * wv.z + x1.w * wv.w;
            acc[2][c] += x2.x * wv.x + x2.y * wv.y + x2.z * wv.z + x2.w * wv.w;
            acc[3][c] += x3.x * wv.x + x3.y * wv.y + x3.z * wv.z + x3.w * wv.w;
        }
    }
#pragma unroll
    for (int r = 0; r < 4; r++) {
        int gr = row0 + ty * 4 + r;
        if (gr < n) {
            float4 o = make_float4(acc[r][0], acc[r][1], acc[r][2], acc[r][3]);
            *(float4*)&Y[gr * 128 + col0 + tx * 4] = o;
        }
    }
}

// -------- CSR gather + fused self-loop/bias/relu: atomic-free --------------
// 32 lanes per node (8 nodes per 256-thread block), float4 per lane.
__global__ __launch_bounds__(256) void gather_csr(const int* __restrict__ cursor,
                                                  const int* __restrict__ srow,
                                                  const float* __restrict__ snorm,
                                                  const float* __restrict__ xw,
                                                  const float* __restrict__ dinv,
                                                  const float* __restrict__ bias,
                                                  float* __restrict__ h) {
    int node = blockIdx.x * 8 + (threadIdx.x >> 5);
    int lane = threadIdx.x & 31;
    if (node >= N_NODES) return;
    int start = node ? cursor[node - 1] : 0;
    int end   = cursor[node];
    float d = dinv[node];
    float s = d * d;
    float4 v0 = ((const float4*)xw)[node * 32 + lane];
    float4 acc = make_float4(s * v0.x, s * v0.y, s * v0.z, s * v0.w);
    if (start < end) {
        int   r = srow[start];
        float w = snorm[start];
        for (int e = start + 1;; ++e) {
            float4 v = ((const float4*)xw)[(size_t)r * 32 + lane];
            bool more = (e < end);
            int rn = 0; float wn = 0.f;
            if (more) { rn = srow[e]; wn = snorm[e]; }
            acc.x += w * v.x; acc.y += w * v.y;
            acc.z += w * v.z; acc.w += w * v.w;
            if (!more) break;
            r = rn; w = wn;
        }
    }
    float4 bb = ((const float4*)bias)[lane];
    acc.x = fmaxf(acc.x + bb.x, 0.f);
    acc.y = fmaxf(acc.y + bb.y, 0.f);
    acc.z = fmaxf(acc.z + bb.z, 0.f);
    acc.w = fmaxf(acc.w + bb.w, 0.f);
    ((float4*)h)[node * 32 + lane] = acc;
}

// ------------- final: out[n] = h[n] . lin_w + lin_b ------------------------
__global__ __launch_bounds__(256) void final_dot(const float* __restrict__ h,
                                                 const float* __restrict__ lw,
                                                 const float* __restrict__ lb,
                                                 float* __restrict__ out) {
    int node = blockIdx.x * 4 + (threadIdx.x >> 6);
    int lane = threadIdx.x & 63;
    if (node >= N_NODES) return;
    float2 hv = ((const float2*)h)[node * 64 + lane];
    float2 wv = ((const float2*)lw)[lane];
    float p = hv.x * wv.x + hv.y * wv.y;
#pragma unroll
    for (int off = 32; off; off >>= 1) p += __shfl_down(p, off);
    if (lane == 0) out[node] = p + lb[0];
}

extern "C" void kernel_launch(void* const* d_in, const int* in_sizes, int n_in,
                              void* d_out, int out_size, void* d_ws, size_t ws_size,
                              hipStream_t stream) {
    const float* x   = (const float*)d_in[0];
    const int*   ei  = (const int*)d_in[1];   // int64 in reference -> int32 on device
    const float* ea  = (const float*)d_in[2];
    const float* W1  = (const float*)d_in[3];
    const float* b1  = (const float*)d_in[4];
    const float* W2  = (const float*)d_in[5];
    const float* b2  = (const float*)d_in[6];
    const float* W3  = (const float*)d_in[7];
    const float* b3  = (const float*)d_in[8];
    const float* lw  = (const float*)d_in[9];
    const float* lb  = (const float*)d_in[10];
    float*       out = (float*)d_out;

    const int* row = ei;        // edge_index[0]
    const int* col = ei + NE;   // edge_index[1]

    const int BS = 256;
    dim3 gGemm((N_NODES + 63) / 64, 2);
    int gEdge   = (NE + BS - 1) / BS;
    int gNode   = (N_NODES + BS - 1) / BS;
    int gFinal  = (N_NODES + 3) / 4;
    int gGather = (N_NODES + 7) / 8;
    int nchunks = (N_NODES + SCAN_CHUNK - 1) / SCAN_CHUNK;

    // workspace layout (4-byte units):
    //   dinv[N] | cursor[N] | bsums[64] | srow[E] | snorm[E] | bufA[N*C] | bufB[N*C]
    float* ws     = (float*)d_ws;
    float* dinv   = ws;
    int*   cursor = (int*)(dinv + N_NODES);
    int*   bsums  = cursor + N_NODES;
    int*   srow   = bsums + 64;
    float* snorm  = (float*)(srow + NE);
    float* bufA   = snorm + NE;
    float* bufB   = bufA + (size_t)N_NODES * C;

    hipMemsetAsync(dinv, 0, N_NODES * sizeof(float), stream);
    hipMemsetAsync(cursor, 0, N_NODES * sizeof(int), stream);
    deg_kernel<<<gEdge, BS, 0, stream>>>(col, ea, dinv);
    dinv_kernel<<<gNode, BS, 0, stream>>>(dinv);

    // CSR build (by destination column)
    count_kernel<<<gEdge, BS, 0, stream>>>(col, cursor);
    scan1_kernel<<<nchunks, BS, 0, stream>>>(cursor, bsums, N_NODES);
    scan2_kernel<<<1, 64, 0, stream>>>(bsums, nchunks);
    scan3_kernel<<<gNode, BS, 0, stream>>>(cursor, bsums, N_NODES);
    fill_kernel<<<gEdge, BS, 0, stream>>>(row, col, ea, dinv, cursor, srow, snorm);

    // layer 1
    gemm128<<<gGemm, BS, 0, stream>>>(x, W1, bufA, N_NODES);
    gather_csr<<<gGather, BS, 0, stream>>>(cursor, srow, snorm, bufA, dinv, b1, bufB);
    // layer 2
    gemm128<<<gGemm, BS, 0, stream>>>(bufB, W2, bufA, N_NODES);
    gather_csr<<<gGather, BS, 0, stream>>>(cursor, srow, snorm, bufA, dinv, b2, bufB);
    // layer 3
    gemm128<<<gGemm, BS, 0, stream>>>(bufB, W3, bufA, N_NODES);
    gather_csr<<<gGather, BS, 0, stream>>>(cursor, srow, snorm, bufA, dinv, b3, bufB);

    final_dot<<<gFinal, BS, 0, stream>>>(bufB, lw, lb, out);
}

// Round 5
// 989.984 us; speedup vs baseline: 12.8398x; 1.0014x over previous
//
#include <hip/hip_runtime.h>

#define N_NODES 100000
#define NE      1600000
#define C       128
#define SCAN_CHUNK 2048

// -------- fused degree-sum + count histogram over destination col ----------
__global__ __launch_bounds__(256) void deg_count_kernel(const int* __restrict__ col,
                                                        const float* __restrict__ ew,
                                                        float* __restrict__ deg,
                                                        int* __restrict__ cnt) {
    int e = blockIdx.x * 256 + threadIdx.x;
    if (e < NE) {
        int c = col[e];
        atomicAdd(&deg[c], ew[e]);
        atomicAdd(&cnt[c], 1);
    }
}

// ---------------- dinv[i] = 1/sqrt(deg[i] + 1.0)  (self-loop weight 1) -----
__global__ __launch_bounds__(256) void dinv_kernel(float* __restrict__ deg) {
    int i = blockIdx.x * 256 + threadIdx.x;
    if (i < N_NODES) {
        float d = deg[i] + 1.0f;          // always > 0
        deg[i] = 1.0f / sqrtf(d);
    }
}

// ---- multi-block exclusive scan over cnt[] (in place), chunk = 2048 -------
__global__ __launch_bounds__(256) void scan1_kernel(int* __restrict__ data,
                                                    int* __restrict__ bsums, int n) {
    __shared__ int lds[256];
    const int chunk = blockIdx.x;
    const int base  = chunk * SCAN_CHUNK;
    const int t     = threadIdx.x;
    int v[8];
    const int idx0 = base + t * 8;
#pragma unroll
    for (int i = 0; i < 8; i++) v[i] = (idx0 + i < n) ? data[idx0 + i] : 0;
    int run = 0;
#pragma unroll
    for (int i = 0; i < 8; i++) { int tmp = v[i]; v[i] = run; run += tmp; }
    lds[t] = run;
    __syncthreads();
    for (int off = 1; off < 256; off <<= 1) {
        int x = (t >= off) ? lds[t - off] : 0;
        __syncthreads();
        lds[t] += x;
        __syncthreads();
    }
    int texcl = t ? lds[t - 1] : 0;
#pragma unroll
    for (int i = 0; i < 8; i++)
        if (idx0 + i < n) data[idx0 + i] = v[i] + texcl;
    if (t == 255) bsums[chunk] = lds[255];
}

__global__ void scan2_kernel(int* __restrict__ bsums, int nchunks) {
    if (blockIdx.x == 0 && threadIdx.x == 0) {
        int run = 0;
        for (int c = 0; c < nchunks; c++) { int t = bsums[c]; bsums[c] = run; run += t; }
    }
}

__global__ __launch_bounds__(256) void scan3_kernel(int* __restrict__ data,
                                                    const int* __restrict__ bsums, int n) {
    int i = blockIdx.x * 256 + threadIdx.x;
    if (i < n) data[i] += bsums[i / SCAN_CHUNK];
}

// ---- fill sorted edge arrays: srow[pos], snorm[pos]; cursor -> inclusive --
__global__ __launch_bounds__(256) void fill_kernel(const int* __restrict__ row,
                                                   const int* __restrict__ col,
                                                   const float* __restrict__ ew,
                                                   const float* __restrict__ dinv,
                                                   int* __restrict__ cursor,
                                                   int* __restrict__ srow,
                                                   float* __restrict__ snorm) {
    int e = blockIdx.x * 256 + threadIdx.x;
    if (e >= NE) return;
    int c = col[e], r = row[e];
    int pos = atomicAdd(&cursor[c], 1);
    srow[pos]  = r;
    snorm[pos] = dinv[r] * ew[e] * dinv[c];
}

// ---------------- GEMM: Y[n][128] = X[n][128] @ W[128][128] ----------------
// 64 rows x 64 cols per block, 256 threads, 4x4 microtile.
// k-loop unroll bounded to 2: full unroll spilled (256 VGPR, 4.3 GB scratch).
__global__ __launch_bounds__(256) void gemm128(const float* __restrict__ X,
                                               const float* __restrict__ W,
                                               float* __restrict__ Y, int n) {
    __shared__ float sX[64 * 132];
    __shared__ float sW[64 * 132];   // sW[j][k] = W[k][col0+j]
    const int row0 = blockIdx.x * 64;
    const int col0 = blockIdx.y * 64;
    const int tid  = threadIdx.x;

    for (int i = tid; i < 64 * 32; i += 256) {
        int r = i >> 5, kq = i & 31;
        int gr = row0 + r;
        float4 v = make_float4(0.f, 0.f, 0.f, 0.f);
        if (gr < n) v = ((const float4*)X)[gr * 32 + kq];
        ((float4*)(sX + r * 132))[kq] = v;
    }
    for (int i = tid; i < 128 * 64; i += 256) {
        int k = i >> 6, j = i & 63;
        sW[j * 132 + k] = W[k * 128 + col0 + j];
    }
    __syncthreads();

    const int ty = tid >> 4, tx = tid & 15;
    const float* xb = sX + (ty * 4) * 132;
    const float* wb = sW + (tx * 4) * 132;
    float acc[4][4] = {};
#pragma unroll 2
    for (int k = 0; k < 128; k += 4) {
        float4 x0 = *(const float4*)(xb + k);
        float4 x1 = *(const float4*)(xb + 132 + k);
        float4 x2 = *(const float4*)(xb + 264 + k);
        float4 x3 = *(const float4*)(xb + 396 + k);
#pragma unroll
        for (int c = 0; c < 4; c++) {
            float4 wv = *(const float4*)(wb + c * 132 + k);
            acc[0][c] += x0.x * wv.x + x0.y * wv.y + x0.z * wv.z + x0.w * wv.w;
            acc[1][c] += x1.x * wv.x + x1.y * wv.y + x1.z * wv.z + x1.w * wv.w;
            acc[2][c] += x2.x * wv.x + x2.y * wv.y + x2.z * wv.z + x2.w * wv.w;
            acc[3][c] += x3.x * wv.x + x3.y * wv.y + x3.z * wv.z + x3.w * wv.w;
        }
    }
#pragma unroll
    for (int r = 0; r < 4; r++) {
        int gr = row0 + ty * 4 + r;
        if (gr < n) {
            float4 o = make_float4(acc[r][0], acc[r][1], acc[r][2], acc[r][3]);
            *(float4*)&Y[gr * 128 + col0 + tx * 4] = o;
        }
    }
}

// -------- CSR gather + fused self-loop/bias/relu: atomic-free --------------
// 32 lanes per node (8 nodes per 256-thread block), float4 per lane.
// Edge loop unrolled x4: 4 independent gathers in flight per group (R4 showed
// 3.85 TB/s @48% peak with 1 in flight -> latency-bound, not BW-bound).
__global__ __launch_bounds__(256) void gather_csr(const int* __restrict__ cursor,
                                                  const int* __restrict__ srow,
                                                  const float* __restrict__ snorm,
                                                  const float* __restrict__ xw,
                                                  const float* __restrict__ dinv,
                                                  const float* __restrict__ bias,
                                                  float* __restrict__ h) {
    int node = blockIdx.x * 8 + (threadIdx.x >> 5);
    int lane = threadIdx.x & 31;
    if (node >= N_NODES) return;
    int start = node ? cursor[node - 1] : 0;
    int end   = cursor[node];
    float d = dinv[node];
    float s = d * d;
    const float4* xw4 = (const float4*)xw;
    float4 v0 = xw4[(size_t)node * 32 + lane];
    float4 acc = make_float4(s * v0.x, s * v0.y, s * v0.z, s * v0.w);

    int e = start;
    for (; e + 4 <= end; e += 4) {
        int   r0 = srow[e + 0], r1 = srow[e + 1], r2 = srow[e + 2], r3 = srow[e + 3];
        float w0 = snorm[e + 0], w1 = snorm[e + 1], w2 = snorm[e + 2], w3 = snorm[e + 3];
        float4 a0 = xw4[(size_t)r0 * 32 + lane];
        float4 a1 = xw4[(size_t)r1 * 32 + lane];
        float4 a2 = xw4[(size_t)r2 * 32 + lane];
        float4 a3 = xw4[(size_t)r3 * 32 + lane];
        acc.x += w0 * a0.x + w1 * a1.x + w2 * a2.x + w3 * a3.x;
        acc.y += w0 * a0.y + w1 * a1.y + w2 * a2.y + w3 * a3.y;
        acc.z += w0 * a0.z + w1 * a1.z + w2 * a2.z + w3 * a3.z;
        acc.w += w0 * a0.w + w1 * a1.w + w2 * a2.w + w3 * a3.w;
    }
    for (; e < end; ++e) {
        int   r = srow[e];
        float w = snorm[e];
        float4 a = xw4[(size_t)r * 32 + lane];
        acc.x += w * a.x; acc.y += w * a.y;
        acc.z += w * a.z; acc.w += w * a.w;
    }

    float4 bb = ((const float4*)bias)[lane];
    acc.x = fmaxf(acc.x + bb.x, 0.f);
    acc.y = fmaxf(acc.y + bb.y, 0.f);
    acc.z = fmaxf(acc.z + bb.z, 0.f);
    acc.w = fmaxf(acc.w + bb.w, 0.f);
    ((float4*)h)[(size_t)node * 32 + lane] = acc;
}

// ------------- final: out[n] = h[n] . lin_w + lin_b ------------------------
__global__ __launch_bounds__(256) void final_dot(const float* __restrict__ h,
                                                 const float* __restrict__ lw,
                                                 const float* __restrict__ lb,
                                                 float* __restrict__ out) {
    int node = blockIdx.x * 4 + (threadIdx.x >> 6);
    int lane = threadIdx.x & 63;
    if (node >= N_NODES) return;
    float2 hv = ((const float2*)h)[node * 64 + lane];
    float2 wv = ((const float2*)lw)[lane];
    float p = hv.x * wv.x + hv.y * wv.y;
#pragma unroll
    for (int off = 32; off; off >>= 1) p += __shfl_down(p, off);
    if (lane == 0) out[node] = p + lb[0];
}

extern "C" void kernel_launch(void* const* d_in, const int* in_sizes, int n_in,
                              void* d_out, int out_size, void* d_ws, size_t ws_size,
                              hipStream_t stream) {
    const float* x   = (const float*)d_in[0];
    const int*   ei  = (const int*)d_in[1];   // int64 in reference -> int32 on device
    const float* ea  = (const float*)d_in[2];
    const float* W1  = (const float*)d_in[3];
    const float* b1  = (const float*)d_in[4];
    const float* W2  = (const float*)d_in[5];
    const float* b2  = (const float*)d_in[6];
    const float* W3  = (const float*)d_in[7];
    const float* b3  = (const float*)d_in[8];
    const float* lw  = (const float*)d_in[9];
    const float* lb  = (const float*)d_in[10];
    float*       out = (float*)d_out;

    const int* row = ei;        // edge_index[0]
    const int* col = ei + NE;   // edge_index[1]

    const int BS = 256;
    dim3 gGemm((N_NODES + 63) / 64, 2);
    int gEdge   = (NE + BS - 1) / BS;
    int gNode   = (N_NODES + BS - 1) / BS;
    int gFinal  = (N_NODES + 3) / 4;
    int gGather = (N_NODES + 7) / 8;
    int nchunks = (N_NODES + SCAN_CHUNK - 1) / SCAN_CHUNK;

    // workspace layout (4-byte units):
    //   dinv[N] | cursor[N] | bsums[64] | srow[E] | snorm[E] | bufA[N*C] | bufB[N*C]
    float* ws     = (float*)d_ws;
    float* dinv   = ws;
    int*   cursor = (int*)(dinv + N_NODES);
    int*   bsums  = cursor + N_NODES;
    int*   srow   = bsums + 64;
    float* snorm  = (float*)(srow + NE);
    float* bufA   = snorm + NE;
    float* bufB   = bufA + (size_t)N_NODES * C;

    hipMemsetAsync(dinv, 0, N_NODES * sizeof(float), stream);
    hipMemsetAsync(cursor, 0, N_NODES * sizeof(int), stream);
    deg_count_kernel<<<gEdge, BS, 0, stream>>>(col, ea, dinv, cursor);
    dinv_kernel<<<gNode, BS, 0, stream>>>(dinv);

    // CSR build (by destination column)
    scan1_kernel<<<nchunks, BS, 0, stream>>>(cursor, bsums, N_NODES);
    scan2_kernel<<<1, 64, 0, stream>>>(bsums, nchunks);
    scan3_kernel<<<gNode, BS, 0, stream>>>(cursor, bsums, N_NODES);
    fill_kernel<<<gEdge, BS, 0, stream>>>(row, col, ea, dinv, cursor, srow, snorm);

    // layer 1
    gemm128<<<gGemm, BS, 0, stream>>>(x, W1, bufA, N_NODES);
    gather_csr<<<gGather, BS, 0, stream>>>(cursor, srow, snorm, bufA, dinv, b1, bufB);
    // layer 2
    gemm128<<<gGemm, BS, 0, stream>>>(bufB, W2, bufA, N_NODES);
    gather_csr<<<gGather, BS, 0, stream>>>(cursor, srow, snorm, bufA, dinv, b2, bufB);
    // layer 3
    gemm128<<<gGemm, BS, 0, stream>>>(bufB, W3, bufA, N_NODES);
    gather_csr<<<gGather, BS, 0, stream>>>(cursor, srow, snorm, bufA, dinv, b3, bufB);

    final_dot<<<gFinal, BS, 0, stream>>>(bufB, lw, lb, out);
}

// Round 6
// 799.525 us; speedup vs baseline: 15.8984x; 1.2382x over previous
//
#include <hip/hip_runtime.h>

#define N_NODES 100000
#define NE      1600000
#define C       128
#define SCAN_CHUNK 2048
#define TWO32 4294967296.0

// ---- fused degree-sum + count histogram: ONE packed double atomic/edge ----
// degcnt[c] accumulates count*2^32 + sum(ew). count <= ~64 exact in high bits;
// ew-sum rounding ~2e-4 -> dinv rel err ~7e-6 (negligible).
__global__ __launch_bounds__(256) void deg_count_kernel(const int* __restrict__ col,
                                                        const float* __restrict__ ew,
                                                        double* __restrict__ degcnt) {
    int e = blockIdx.x * 256 + threadIdx.x;
    if (e < NE) atomicAdd(&degcnt[col[e]], TWO32 + (double)ew[e]);
}

// ---- unpack: dinv[i] = rsqrt(deg+1), cnt[i] = edge count ------------------
__global__ __launch_bounds__(256) void dinv_kernel(const double* __restrict__ degcnt,
                                                   float* __restrict__ dinv,
                                                   int* __restrict__ cnt) {
    int i = blockIdx.x * 256 + threadIdx.x;
    if (i < N_NODES) {
        double v = degcnt[i];
        double c = floor(v * (1.0 / TWO32));
        float deg = (float)(v - c * TWO32) + 1.0f;   // + self-loop weight 1
        dinv[i] = 1.0f / sqrtf(deg);
        cnt[i]  = (int)c;
    }
}

// ---- multi-block exclusive scan over cnt[] (in place), chunk = 2048 -------
__global__ __launch_bounds__(256) void scan1_kernel(int* __restrict__ data,
                                                    int* __restrict__ bsums, int n) {
    __shared__ int lds[256];
    const int chunk = blockIdx.x;
    const int base  = chunk * SCAN_CHUNK;
    const int t     = threadIdx.x;
    int v[8];
    const int idx0 = base + t * 8;
#pragma unroll
    for (int i = 0; i < 8; i++) v[i] = (idx0 + i < n) ? data[idx0 + i] : 0;
    int run = 0;
#pragma unroll
    for (int i = 0; i < 8; i++) { int tmp = v[i]; v[i] = run; run += tmp; }
    lds[t] = run;
    __syncthreads();
    for (int off = 1; off < 256; off <<= 1) {
        int x = (t >= off) ? lds[t - off] : 0;
        __syncthreads();
        lds[t] += x;
        __syncthreads();
    }
    int texcl = t ? lds[t - 1] : 0;
#pragma unroll
    for (int i = 0; i < 8; i++)
        if (idx0 + i < n) data[idx0 + i] = v[i] + texcl;
    if (t == 255) bsums[chunk] = lds[255];
}

__global__ void scan2_kernel(int* __restrict__ bsums, int nchunks) {
    if (blockIdx.x == 0 && threadIdx.x == 0) {
        int run = 0;
        for (int c = 0; c < nchunks; c++) { int t = bsums[c]; bsums[c] = run; run += t; }
    }
}

__global__ __launch_bounds__(256) void scan3_kernel(int* __restrict__ data,
                                                    const int* __restrict__ bsums, int n) {
    int i = blockIdx.x * 256 + threadIdx.x;
    if (i < n) data[i] += bsums[i / SCAN_CHUNK];
}

// ---- fill sorted edge arrays: srow[pos], snorm[pos]; cursor -> inclusive --
__global__ __launch_bounds__(256) void fill_kernel(const int* __restrict__ row,
                                                   const int* __restrict__ col,
                                                   const float* __restrict__ ew,
                                                   const float* __restrict__ dinv,
                                                   int* __restrict__ cursor,
                                                   int* __restrict__ srow,
                                                   float* __restrict__ snorm) {
    int e = blockIdx.x * 256 + threadIdx.x;
    if (e >= NE) return;
    int c = col[e], r = row[e];
    int pos = atomicAdd(&cursor[c], 1);
    srow[pos]  = r;
    snorm[pos] = dinv[r] * ew[e] * dinv[c];
}

// ---- fp32 -> bf16 (round-to-nearest-even) packing helpers -----------------
__device__ __forceinline__ unsigned int bf16rne(float f) {
    unsigned int u = __float_as_uint(f);
    return (u + 0x7FFFu + ((u >> 16) & 1u)) >> 16;
}

// ---------------- GEMM: Yb[n][128] = bf16( X[n][128] @ W[128][128] ) -------
// 64 rows x 64 cols per block, 256 threads, 4x4 microtile.
// k-loop unroll bounded to 2: full unroll spilled (256 VGPR, 4.3 GB scratch).
// Output written ONLY as bf16 (halves gather-side traffic; h stays fp32).
__global__ __launch_bounds__(256) void gemm128(const float* __restrict__ X,
                                               const float* __restrict__ W,
                                               unsigned int* __restrict__ Yb,  // 2 bf16 per uint
                                               int n) {
    __shared__ float sX[64 * 132];
    __shared__ float sW[64 * 132];   // sW[j][k] = W[k][col0+j]
    const int row0 = blockIdx.x * 64;
    const int col0 = blockIdx.y * 64;
    const int tid  = threadIdx.x;

    for (int i = tid; i < 64 * 32; i += 256) {
        int r = i >> 5, kq = i & 31;
        int gr = row0 + r;
        float4 v = make_float4(0.f, 0.f, 0.f, 0.f);
        if (gr < n) v = ((const float4*)X)[gr * 32 + kq];
        ((float4*)(sX + r * 132))[kq] = v;
    }
    for (int i = tid; i < 128 * 64; i += 256) {
        int k = i >> 6, j = i & 63;
        sW[j * 132 + k] = W[k * 128 + col0 + j];
    }
    __syncthreads();

    const int ty = tid >> 4, tx = tid & 15;
    const float* xb = sX + (ty * 4) * 132;
    const float* wb = sW + (tx * 4) * 132;
    float acc[4][4] = {};
#pragma unroll 2
    for (int k = 0; k < 128; k += 4) {
        float4 x0 = *(const float4*)(xb + k);
        float4 x1 = *(const float4*)(xb + 132 + k);
        float4 x2 = *(const float4*)(xb + 264 + k);
        float4 x3 = *(const float4*)(xb + 396 + k);
#pragma unroll
        for (int c = 0; c < 4; c++) {
            float4 wv = *(const float4*)(wb + c * 132 + k);
            acc[0][c] += x0.x * wv.x + x0.y * wv.y + x0.z * wv.z + x0.w * wv.w;
            acc[1][c] += x1.x * wv.x + x1.y * wv.y + x1.z * wv.z + x1.w * wv.w;
            acc[2][c] += x2.x * wv.x + x2.y * wv.y + x2.z * wv.z + x2.w * wv.w;
            acc[3][c] += x3.x * wv.x + x3.y * wv.y + x3.z * wv.z + x3.w * wv.w;
        }
    }
#pragma unroll
    for (int r = 0; r < 4; r++) {
        int gr = row0 + ty * 4 + r;
        if (gr < n) {
            uint2 o;
            o.x = bf16rne(acc[r][0]) | (bf16rne(acc[r][1]) << 16);
            o.y = bf16rne(acc[r][2]) | (bf16rne(acc[r][3]) << 16);
            // uint2 units of 4 cols: 32 per row
            ((uint2*)Yb)[(size_t)gr * 32 + (col0 >> 2) + tx] = o;
        }
    }
}

// -------- CSR gather (bf16 table) + fused self-loop/bias/relu --------------
// 32 lanes per node, each lane owns 4 cols: one uint2 (4 bf16) per edge.
// Main loop 8-wide for MLP; fp32 accumulation; h written fp32.
__global__ __launch_bounds__(256) void gather_csr(const int* __restrict__ cursor,
                                                  const int* __restrict__ srow,
                                                  const float* __restrict__ snorm,
                                                  const unsigned int* __restrict__ xwb,
                                                  const float* __restrict__ dinv,
                                                  const float* __restrict__ bias,
                                                  float* __restrict__ h) {
    int node = blockIdx.x * 8 + (threadIdx.x >> 5);
    int lane = threadIdx.x & 31;
    if (node >= N_NODES) return;
    int start = node ? cursor[node - 1] : 0;
    int end   = cursor[node];
    const uint2* tab = (const uint2*)xwb;   // 32 uint2 per node row

    float d = dinv[node];
    float s = d * d;
    uint2 q0 = tab[(size_t)node * 32 + lane];
    float4 acc;
    acc.x = s * __uint_as_float(q0.x << 16);
    acc.y = s * __uint_as_float(q0.x & 0xFFFF0000u);
    acc.z = s * __uint_as_float(q0.y << 16);
    acc.w = s * __uint_as_float(q0.y & 0xFFFF0000u);

    int e = start;
    for (; e + 8 <= end; e += 8) {
        uint2 q[8]; float w[8];
#pragma unroll
        for (int j = 0; j < 8; j++) {
            int r = srow[e + j];
            w[j] = snorm[e + j];
            q[j] = tab[(size_t)r * 32 + lane];
        }
#pragma unroll
        for (int j = 0; j < 8; j++) {
            acc.x += w[j] * __uint_as_float(q[j].x << 16);
            acc.y += w[j] * __uint_as_float(q[j].x & 0xFFFF0000u);
            acc.z += w[j] * __uint_as_float(q[j].y << 16);
            acc.w += w[j] * __uint_as_float(q[j].y & 0xFFFF0000u);
        }
    }
    for (; e < end; ++e) {
        int   r = srow[e];
        float w = snorm[e];
        uint2 q = tab[(size_t)r * 32 + lane];
        acc.x += w * __uint_as_float(q.x << 16);
        acc.y += w * __uint_as_float(q.x & 0xFFFF0000u);
        acc.z += w * __uint_as_float(q.y << 16);
        acc.w += w * __uint_as_float(q.y & 0xFFFF0000u);
    }

    float4 bb = ((const float4*)bias)[lane];
    acc.x = fmaxf(acc.x + bb.x, 0.f);
    acc.y = fmaxf(acc.y + bb.y, 0.f);
    acc.z = fmaxf(acc.z + bb.z, 0.f);
    acc.w = fmaxf(acc.w + bb.w, 0.f);
    ((float4*)h)[(size_t)node * 32 + lane] = acc;
}

// ------------- final: out[n] = h[n] . lin_w + lin_b ------------------------
__global__ __launch_bounds__(256) void final_dot(const float* __restrict__ h,
                                                 const float* __restrict__ lw,
                                                 const float* __restrict__ lb,
                                                 float* __restrict__ out) {
    int node = blockIdx.x * 4 + (threadIdx.x >> 6);
    int lane = threadIdx.x & 63;
    if (node >= N_NODES) return;
    float2 hv = ((const float2*)h)[node * 64 + lane];
    float2 wv = ((const float2*)lw)[lane];
    float p = hv.x * wv.x + hv.y * wv.y;
#pragma unroll
    for (int off = 32; off; off >>= 1) p += __shfl_down(p, off);
    if (lane == 0) out[node] = p + lb[0];
}

extern "C" void kernel_launch(void* const* d_in, const int* in_sizes, int n_in,
                              void* d_out, int out_size, void* d_ws, size_t ws_size,
                              hipStream_t stream) {
    const float* x   = (const float*)d_in[0];
    const int*   ei  = (const int*)d_in[1];   // int64 in reference -> int32 on device
    const float* ea  = (const float*)d_in[2];
    const float* W1  = (const float*)d_in[3];
    const float* b1  = (const float*)d_in[4];
    const float* W2  = (const float*)d_in[5];
    const float* b2  = (const float*)d_in[6];
    const float* W3  = (const float*)d_in[7];
    const float* b3  = (const float*)d_in[8];
    const float* lw  = (const float*)d_in[9];
    const float* lb  = (const float*)d_in[10];
    float*       out = (float*)d_out;

    const int* row = ei;        // edge_index[0]
    const int* col = ei + NE;   // edge_index[1]

    const int BS = 256;
    dim3 gGemm((N_NODES + 63) / 64, 2);
    int gEdge   = (NE + BS - 1) / BS;
    int gNode   = (N_NODES + BS - 1) / BS;
    int gFinal  = (N_NODES + 3) / 4;
    int gGather = (N_NODES + 7) / 8;
    int nchunks = (N_NODES + SCAN_CHUNK - 1) / SCAN_CHUNK;

    // workspace layout (~91 MB):
    //   degcnt dbl[N] | dinv f[N] | cursor i[N] | bsums i[64] | srow i[E] |
    //   snorm f[E] | xwb bf16[N*C] | h f[N*C]
    char* wsb = (char*)d_ws;
    double*       degcnt = (double*)wsb;                         wsb += (size_t)N_NODES * 8;
    float*        dinv   = (float*)wsb;                          wsb += (size_t)N_NODES * 4;
    int*          cursor = (int*)wsb;                            wsb += (size_t)N_NODES * 4;
    int*          bsums  = (int*)wsb;                            wsb += 64 * 4;
    int*          srow   = (int*)wsb;                            wsb += (size_t)NE * 4;
    float*        snorm  = (float*)wsb;                          wsb += (size_t)NE * 4;
    unsigned int* xwb    = (unsigned int*)wsb;                   wsb += (size_t)N_NODES * C * 2;
    float*        hbuf   = (float*)wsb;

    hipMemsetAsync(degcnt, 0, (size_t)N_NODES * 8, stream);
    deg_count_kernel<<<gEdge, BS, 0, stream>>>(col, ea, degcnt);
    dinv_kernel<<<gNode, BS, 0, stream>>>(degcnt, dinv, cursor);

    // CSR build (by destination column)
    scan1_kernel<<<nchunks, BS, 0, stream>>>(cursor, bsums, N_NODES);
    scan2_kernel<<<1, 64, 0, stream>>>(bsums, nchunks);
    scan3_kernel<<<gNode, BS, 0, stream>>>(cursor, bsums, N_NODES);
    fill_kernel<<<gEdge, BS, 0, stream>>>(row, col, ea, dinv, cursor, srow, snorm);

    // layer 1
    gemm128<<<gGemm, BS, 0, stream>>>(x, W1, xwb, N_NODES);
    gather_csr<<<gGather, BS, 0, stream>>>(cursor, srow, snorm, xwb, dinv, b1, hbuf);
    // layer 2
    gemm128<<<gGemm, BS, 0, stream>>>(hbuf, W2, xwb, N_NODES);
    gather_csr<<<gGather, BS, 0, stream>>>(cursor, srow, snorm, xwb, dinv, b2, hbuf);
    // layer 3
    gemm128<<<gGemm, BS, 0, stream>>>(hbuf, W3, xwb, N_NODES);
    gather_csr<<<gGather, BS, 0, stream>>>(cursor, srow, snorm, xwb, dinv, b3, hbuf);

    final_dot<<<gFinal, BS, 0, stream>>>(hbuf, lw, lb, out);
}

// Round 7
// 557.513 us; speedup vs baseline: 22.7998x; 1.4341x over previous
//
#include <hip/hip_runtime.h>

#define N_NODES 100000
#define NE      1600000
#define C       128
#define SCAN_CHUNK 2048
#define TWO32 4294967296.0

typedef __attribute__((ext_vector_type(8))) short short8;
typedef __attribute__((ext_vector_type(4))) float float4v;

__device__ __forceinline__ unsigned short bf16rne(float f) {
    unsigned int u = __float_as_uint(f);
    return (unsigned short)((u + 0x7FFFu + ((u >> 16) & 1u)) >> 16);
}

// ---- fused degree-sum + count histogram: ONE packed double atomic/edge ----
__global__ __launch_bounds__(256) void deg_count_kernel(const int* __restrict__ col,
                                                        const float* __restrict__ ew,
                                                        double* __restrict__ degcnt) {
    int e = blockIdx.x * 256 + threadIdx.x;
    if (e < NE) atomicAdd(&degcnt[col[e]], TWO32 + (double)ew[e]);
}

// ---- unpack: dinv[i] = rsqrt(deg+1), cnt[i] = edge count ------------------
__global__ __launch_bounds__(256) void dinv_kernel(const double* __restrict__ degcnt,
                                                   float* __restrict__ dinv,
                                                   int* __restrict__ cnt) {
    int i = blockIdx.x * 256 + threadIdx.x;
    if (i < N_NODES) {
        double v = degcnt[i];
        double c = floor(v * (1.0 / TWO32));
        float deg = (float)(v - c * TWO32) + 1.0f;   // + self-loop weight 1
        dinv[i] = 1.0f / sqrtf(deg);
        cnt[i]  = (int)c;
    }
}

// ---- multi-block exclusive scan over cnt[] (in place), chunk = 2048 -------
__global__ __launch_bounds__(256) void scan1_kernel(int* __restrict__ data,
                                                    int* __restrict__ bsums, int n) {
    __shared__ int lds[256];
    const int chunk = blockIdx.x;
    const int base  = chunk * SCAN_CHUNK;
    const int t     = threadIdx.x;
    int v[8];
    const int idx0 = base + t * 8;
#pragma unroll
    for (int i = 0; i < 8; i++) v[i] = (idx0 + i < n) ? data[idx0 + i] : 0;
    int run = 0;
#pragma unroll
    for (int i = 0; i < 8; i++) { int tmp = v[i]; v[i] = run; run += tmp; }
    lds[t] = run;
    __syncthreads();
    for (int off = 1; off < 256; off <<= 1) {
        int x = (t >= off) ? lds[t - off] : 0;
        __syncthreads();
        lds[t] += x;
        __syncthreads();
    }
    int texcl = t ? lds[t - 1] : 0;
#pragma unroll
    for (int i = 0; i < 8; i++)
        if (idx0 + i < n) data[idx0 + i] = v[i] + texcl;
    if (t == 255) bsums[chunk] = lds[255];
}

__global__ void scan2_kernel(int* __restrict__ bsums, int nchunks) {
    if (blockIdx.x == 0 && threadIdx.x == 0) {
        int run = 0;
        for (int c = 0; c < nchunks; c++) { int t = bsums[c]; bsums[c] = run; run += t; }
    }
}

__global__ __launch_bounds__(256) void scan3_kernel(int* __restrict__ data,
                                                    const int* __restrict__ bsums, int n) {
    int i = blockIdx.x * 256 + threadIdx.x;
    if (i < n) data[i] += bsums[i / SCAN_CHUNK];
}

// ---- fill sorted edges: ONE packed 8B write {row, normbits} per edge ------
__global__ __launch_bounds__(256) void fill_kernel(const int* __restrict__ row,
                                                   const int* __restrict__ col,
                                                   const float* __restrict__ ew,
                                                   const float* __restrict__ dinv,
                                                   int* __restrict__ cursor,
                                                   uint2* __restrict__ sedge) {
    int e = blockIdx.x * 256 + threadIdx.x;
    if (e >= NE) return;
    int c = col[e], r = row[e];
    int pos = atomicAdd(&cursor[c], 1);
    float nrm = dinv[r] * ew[e] * dinv[c];
    sedge[pos] = make_uint2((unsigned int)r, __float_as_uint(nrm));
}

// ---- Wt[n][k] = bf16(W[k][n]): small per-layer transpose+cast -------------
__global__ __launch_bounds__(256) void wt_kernel(const float* __restrict__ W,
                                                 unsigned short* __restrict__ Wt) {
    int i = blockIdx.x * 256 + threadIdx.x;   // 16384 elems
    int n = i >> 7, k = i & 127;
    Wt[i] = bf16rne(W[k * 128 + n]);          // Wt[n*128+k]
}

// ---------------- MFMA GEMM: Yb[n][128] = bf16( X @ W ) --------------------
// 64-row x 128-col tile per block (4 waves x 16 rows), 16x16x32 bf16 MFMA.
// X fp32 -> bf16 during LDS staging; Wt pre-transposed bf16 [n][k].
// LDS rows padded to 136 ushorts (16B-aligned, 2-way banks = free).
__global__ __launch_bounds__(256) void gemm_mfma(const float* __restrict__ X,
                                                 const unsigned short* __restrict__ Wt,
                                                 unsigned short* __restrict__ Yb,
                                                 int n) {
    __shared__ unsigned short sA[64 * 136];   // [m][k]
    __shared__ unsigned short sB[128 * 136];  // [n][k]
    const int row0 = blockIdx.x * 64;
    const int tid  = threadIdx.x;

    // stage A: 64 rows x 32 float4, convert to bf16
    for (int i = tid; i < 64 * 32; i += 256) {
        int r = i >> 5, q = i & 31;
        int gr = row0 + r;
        float4 v = make_float4(0.f, 0.f, 0.f, 0.f);
        if (gr < n) v = ((const float4*)X)[(size_t)gr * 32 + q];
        ushort4 o;
        o.x = bf16rne(v.x); o.y = bf16rne(v.y);
        o.z = bf16rne(v.z); o.w = bf16rne(v.w);
        *(ushort4*)&sA[r * 136 + q * 4] = o;
    }
    // stage B: copy Wt (bf16, already [n][k]) in uint4 chunks
    for (int i = tid; i < 128 * 16; i += 256) {
        int nr = i >> 4, q = i & 15;
        *(uint4*)&sB[nr * 136 + q * 8] = ((const uint4*)Wt)[i];
    }
    __syncthreads();

    const int wave = tid >> 6, lane = tid & 63;
    const int m = lane & 15, quad = lane >> 4;

    float4v acc[8];
#pragma unroll
    for (int t = 0; t < 8; t++) acc[t] = (float4v){0.f, 0.f, 0.f, 0.f};

    const unsigned short* pa = &sA[(wave * 16 + m) * 136 + quad * 8];
#pragma unroll
    for (int kc = 0; kc < 4; kc++) {
        short8 a = *(const short8*)(pa + kc * 32);
#pragma unroll
        for (int t = 0; t < 8; t++) {
            short8 b = *(const short8*)&sB[(t * 16 + m) * 136 + kc * 32 + quad * 8];
            acc[t] = __builtin_amdgcn_mfma_f32_16x16x32_bf16(a, b, acc[t], 0, 0, 0);
        }
    }
    // C/D layout: col = lane&15, row = quad*4 + reg
#pragma unroll
    for (int t = 0; t < 8; t++) {
#pragma unroll
        for (int r = 0; r < 4; r++) {
            int gr = row0 + wave * 16 + quad * 4 + r;
            if (gr < n) Yb[(size_t)gr * 128 + t * 16 + m] = bf16rne(acc[t][r]);
        }
    }
}

// -------- CSR gather (bf16 table, packed edges) + self-loop/bias/relu ------
// 32 lanes per node, each lane owns 4 cols (uint2 = 4 bf16 per edge).
__global__ __launch_bounds__(256) void gather_csr(const int* __restrict__ cursor,
                                                  const uint2* __restrict__ sedge,
                                                  const unsigned short* __restrict__ xwb,
                                                  const float* __restrict__ dinv,
                                                  const float* __restrict__ bias,
                                                  float* __restrict__ h) {
    int node = blockIdx.x * 8 + (threadIdx.x >> 5);
    int lane = threadIdx.x & 31;
    if (node >= N_NODES) return;
    int start = node ? cursor[node - 1] : 0;
    int end   = cursor[node];
    const uint2* tab = (const uint2*)xwb;   // 32 uint2 per node row

    float d = dinv[node];
    float s = d * d;
    uint2 q0 = tab[(size_t)node * 32 + lane];
    float4 acc;
    acc.x = s * __uint_as_float(q0.x << 16);
    acc.y = s * __uint_as_float(q0.x & 0xFFFF0000u);
    acc.z = s * __uint_as_float(q0.y << 16);
    acc.w = s * __uint_as_float(q0.y & 0xFFFF0000u);

    int e = start;
    for (; e + 4 <= end; e += 4) {
        uint2 E[4]; uint2 q[4];
#pragma unroll
        for (int j = 0; j < 4; j++) E[j] = sedge[e + j];
#pragma unroll
        for (int j = 0; j < 4; j++) q[j] = tab[(size_t)E[j].x * 32 + lane];
#pragma unroll
        for (int j = 0; j < 4; j++) {
            float w = __uint_as_float(E[j].y);
            acc.x += w * __uint_as_float(q[j].x << 16);
            acc.y += w * __uint_as_float(q[j].x & 0xFFFF0000u);
            acc.z += w * __uint_as_float(q[j].y << 16);
            acc.w += w * __uint_as_float(q[j].y & 0xFFFF0000u);
        }
    }
    for (; e < end; ++e) {
        uint2 E = sedge[e];
        float w = __uint_as_float(E.y);
        uint2 q = tab[(size_t)E.x * 32 + lane];
        acc.x += w * __uint_as_float(q.x << 16);
        acc.y += w * __uint_as_float(q.x & 0xFFFF0000u);
        acc.z += w * __uint_as_float(q.y << 16);
        acc.w += w * __uint_as_float(q.y & 0xFFFF0000u);
    }

    float4 bb = ((const float4*)bias)[lane];
    acc.x = fmaxf(acc.x + bb.x, 0.f);
    acc.y = fmaxf(acc.y + bb.y, 0.f);
    acc.z = fmaxf(acc.z + bb.z, 0.f);
    acc.w = fmaxf(acc.w + bb.w, 0.f);
    ((float4*)h)[(size_t)node * 32 + lane] = acc;
}

// ------------- final: out[n] = h[n] . lin_w + lin_b ------------------------
__global__ __launch_bounds__(256) void final_dot(const float* __restrict__ h,
                                                 const float* __restrict__ lw,
                                                 const float* __restrict__ lb,
                                                 float* __restrict__ out) {
    int node = blockIdx.x * 4 + (threadIdx.x >> 6);
    int lane = threadIdx.x & 63;
    if (node >= N_NODES) return;
    float2 hv = ((const float2*)h)[node * 64 + lane];
    float2 wv = ((const float2*)lw)[lane];
    float p = hv.x * wv.x + hv.y * wv.y;
#pragma unroll
    for (int off = 32; off; off >>= 1) p += __shfl_down(p, off);
    if (lane == 0) out[node] = p + lb[0];
}

extern "C" void kernel_launch(void* const* d_in, const int* in_sizes, int n_in,
                              void* d_out, int out_size, void* d_ws, size_t ws_size,
                              hipStream_t stream) {
    const float* x   = (const float*)d_in[0];
    const int*   ei  = (const int*)d_in[1];   // int64 in reference -> int32 on device
    const float* ea  = (const float*)d_in[2];
    const float* W1  = (const float*)d_in[3];
    const float* b1  = (const float*)d_in[4];
    const float* W2  = (const float*)d_in[5];
    const float* b2  = (const float*)d_in[6];
    const float* W3  = (const float*)d_in[7];
    const float* b3  = (const float*)d_in[8];
    const float* lw  = (const float*)d_in[9];
    const float* lb  = (const float*)d_in[10];
    float*       out = (float*)d_out;

    const int* row = ei;        // edge_index[0]
    const int* col = ei + NE;   // edge_index[1]

    const int BS = 256;
    int gEdge   = (NE + BS - 1) / BS;
    int gNode   = (N_NODES + BS - 1) / BS;
    int gFinal  = (N_NODES + 3) / 4;
    int gGather = (N_NODES + 7) / 8;
    int gGemm   = (N_NODES + 63) / 64;
    int nchunks = (N_NODES + SCAN_CHUNK - 1) / SCAN_CHUNK;

    // workspace layout (~91 MB):
    //   degcnt dbl[N] | sedge uint2[E] | dinv f[N] | cursor i[N] | bsums i[64]
    //   | Wt u16[16384] | xwb u16[N*C] | h f[N*C]
    char* wsb = (char*)d_ws;
    double*         degcnt = (double*)wsb;        wsb += (size_t)N_NODES * 8;
    uint2*          sedge  = (uint2*)wsb;         wsb += (size_t)NE * 8;
    float*          dinv   = (float*)wsb;         wsb += (size_t)N_NODES * 4;
    int*            cursor = (int*)wsb;           wsb += (size_t)N_NODES * 4;
    int*            bsums  = (int*)wsb;           wsb += 64 * 4;
    unsigned short* Wt     = (unsigned short*)wsb; wsb += 16384 * 2;
    unsigned short* xwb    = (unsigned short*)wsb; wsb += (size_t)N_NODES * C * 2;
    float*          hbuf   = (float*)wsb;

    hipMemsetAsync(degcnt, 0, (size_t)N_NODES * 8, stream);
    deg_count_kernel<<<gEdge, BS, 0, stream>>>(col, ea, degcnt);
    dinv_kernel<<<gNode, BS, 0, stream>>>(degcnt, dinv, cursor);

    // CSR build (by destination column)
    scan1_kernel<<<nchunks, BS, 0, stream>>>(cursor, bsums, N_NODES);
    scan2_kernel<<<1, 64, 0, stream>>>(bsums, nchunks);
    scan3_kernel<<<gNode, BS, 0, stream>>>(cursor, bsums, N_NODES);
    fill_kernel<<<gEdge, BS, 0, stream>>>(row, col, ea, dinv, cursor, sedge);

    // layer 1
    wt_kernel<<<64, BS, 0, stream>>>(W1, Wt);
    gemm_mfma<<<gGemm, BS, 0, stream>>>(x, Wt, xwb, N_NODES);
    gather_csr<<<gGather, BS, 0, stream>>>(cursor, sedge, xwb, dinv, b1, hbuf);
    // layer 2
    wt_kernel<<<64, BS, 0, stream>>>(W2, Wt);
    gemm_mfma<<<gGemm, BS, 0, stream>>>(hbuf, Wt, xwb, N_NODES);
    gather_csr<<<gGather, BS, 0, stream>>>(cursor, sedge, xwb, dinv, b2, hbuf);
    // layer 3
    wt_kernel<<<64, BS, 0, stream>>>(W3, Wt);
    gemm_mfma<<<gGemm, BS, 0, stream>>>(hbuf, Wt, xwb, N_NODES);
    gather_csr<<<gGather, BS, 0, stream>>>(cursor, sedge, xwb, dinv, b3, hbuf);

    final_dot<<<gFinal, BS, 0, stream>>>(hbuf, lw, lb, out);
}

// Round 8
// 492.273 us; speedup vs baseline: 25.8214x; 1.1325x over previous
//
#include <hip/hip_runtime.h>

#define N_NODES 100000
#define NE      1600000
#define C       128
#define NB      98        // buckets of 1024 destination nodes: (100000+1023)>>10
#define BCAP    20480     // per-bucket capacity; mean 16384, sigma ~127 -> 32-sigma margin
#define EPB     2048      // edges per binA block

typedef __attribute__((ext_vector_type(8))) short short8;
typedef __attribute__((ext_vector_type(4))) float float4v;

__device__ __forceinline__ unsigned short bf16rne(float f) {
    unsigned int u = __float_as_uint(f);
    return (unsigned short)((u + 0x7FFFu + ((u >> 16) & 1u)) >> 16);
}

// ---- binA: coarse-bucket edges by c>>10, block-aggregated appends ---------
// record = { (c_low<<17) | r , ew_bits }  (c_low 10 bits, r 17 bits)
__global__ __launch_bounds__(256) void binA_kernel(const int* __restrict__ row,
                                                   const int* __restrict__ col,
                                                   const float* __restrict__ ew,
                                                   int* __restrict__ gbcur,
                                                   uint2* __restrict__ babuf) {
    __shared__ int hcnt[NB];
    __shared__ int hofs[NB];
    __shared__ int hbase[NB];
    const int t = threadIdx.x;
    for (int i = t; i < NB; i += 256) { hcnt[i] = 0; hofs[i] = 0; }
    __syncthreads();

    const int e0 = blockIdx.x * EPB;
    int cc[8], rr[8]; float ee[8];
#pragma unroll
    for (int i = 0; i < 8; i++) {
        int e = e0 + i * 256 + t;
        if (e < NE) { cc[i] = col[e]; rr[i] = row[e]; ee[i] = ew[e]; }
        else cc[i] = -1;
    }
#pragma unroll
    for (int i = 0; i < 8; i++)
        if (cc[i] >= 0) atomicAdd(&hcnt[cc[i] >> 10], 1);
    __syncthreads();
    if (t < NB && hcnt[t] > 0) hbase[t] = atomicAdd(&gbcur[t], hcnt[t]);
    __syncthreads();
#pragma unroll
    for (int i = 0; i < 8; i++) {
        if (cc[i] < 0) continue;
        int b = cc[i] >> 10;
        int pos = hbase[b] + atomicAdd(&hofs[b], 1);
        if (pos < BCAP) {
            unsigned int meta = ((unsigned int)(cc[i] & 1023) << 17) | (unsigned int)rr[i];
            babuf[(size_t)b * BCAP + pos] = make_uint2(meta, __float_as_uint(ee[i]));
        }
    }
}

// ---- binB: per-bucket histogram + weighted degree + scan + local scatter --
// Produces: dinv[n], cursor2[n]={start,end} (bucket-strided positions), sedge.
__global__ __launch_bounds__(256) void binB_kernel(const int* __restrict__ gbcur,
                                                   const uint2* __restrict__ babuf,
                                                   float* __restrict__ dinv,
                                                   uint2* __restrict__ cursor2,
                                                   uint2* __restrict__ sedge) {
    __shared__ int   cnt[1024];
    __shared__ float deg[1024];
    __shared__ int   ofs[1024];
    __shared__ int   tsum[256];
    const int b = blockIdx.x, t = threadIdx.x;
    const int n0 = b << 10;
    const int nn = min(1024, N_NODES - n0);

    for (int i = t; i < 1024; i += 256) { cnt[i] = 0; deg[i] = 0.f; }
    __syncthreads();

    const int msize = min(gbcur[b], BCAP);
    const uint2* bb = babuf + (size_t)b * BCAP;
    for (int i = t; i < msize; i += 256) {
        uint2 m = bb[i];
        int cl = m.x >> 17;
        atomicAdd(&cnt[cl], 1);
        atomicAdd(&deg[cl], __uint_as_float(m.y));
    }
    __syncthreads();

    // dinv (weighted in-degree + self-loop weight 1)
    for (int i = t; i < nn; i += 256)
        dinv[n0 + i] = 1.0f / sqrtf(deg[i] + 1.0f);

    // exclusive scan of cnt[1024]: 4 per thread + Hillis-Steele over 256
    const int b4 = t * 4;
    int c0 = cnt[b4], c1 = cnt[b4 + 1], c2 = cnt[b4 + 2], c3 = cnt[b4 + 3];
    tsum[t] = c0 + c1 + c2 + c3;
    __syncthreads();
    for (int off = 1; off < 256; off <<= 1) {
        int v = (t >= off) ? tsum[t - off] : 0;
        __syncthreads();
        tsum[t] += v;
        __syncthreads();
    }
    int texcl = t ? tsum[t - 1] : 0;
    ofs[b4]     = texcl;
    ofs[b4 + 1] = texcl + c0;
    ofs[b4 + 2] = texcl + c0 + c1;
    ofs[b4 + 3] = texcl + c0 + c1 + c2;
    __syncthreads();

    // per-node absolute {start,end} into bucket-strided sedge
    const unsigned int ebase = (unsigned int)b * BCAP;
    for (int i = t; i < nn; i += 256) {
        unsigned int st = ebase + (unsigned int)ofs[i];
        cursor2[n0 + i] = make_uint2(st, st + (unsigned int)cnt[i]);
    }
    __syncthreads();

    // scatter within bucket (writes land in a ~160KB L2-resident region)
    for (int i = t; i < msize; i += 256) {
        uint2 m = bb[i];
        int cl = m.x >> 17;
        int p = atomicAdd(&ofs[cl], 1);
        sedge[(size_t)b * BCAP + p] = make_uint2(m.x & 0x1FFFFu, m.y);
    }
}

// ---- Wt[n][k] = bf16(W[k][n]): small per-layer transpose+cast -------------
__global__ __launch_bounds__(256) void wt_kernel(const float* __restrict__ W,
                                                 unsigned short* __restrict__ Wt) {
    int i = blockIdx.x * 256 + threadIdx.x;   // 16384 elems
    int n = i >> 7, k = i & 127;
    Wt[i] = bf16rne(W[k * 128 + n]);          // Wt[n*128+k]
}

// ---------------- MFMA GEMM: T[n][128] = bf16( dinv[n] * (X @ W) ) ---------
// 64-row x 128-col tile per block (4 waves x 16 rows), 16x16x32 bf16 MFMA.
__global__ __launch_bounds__(256) void gemm_mfma(const float* __restrict__ X,
                                                 const unsigned short* __restrict__ Wt,
                                                 const float* __restrict__ dinv,
                                                 unsigned short* __restrict__ Yb,
                                                 int n) {
    __shared__ unsigned short sA[64 * 136];   // [m][k]
    __shared__ unsigned short sB[128 * 136];  // [n][k]
    const int row0 = blockIdx.x * 64;
    const int tid  = threadIdx.x;

    for (int i = tid; i < 64 * 32; i += 256) {
        int r = i >> 5, q = i & 31;
        int gr = row0 + r;
        float4 v = make_float4(0.f, 0.f, 0.f, 0.f);
        if (gr < n) v = ((const float4*)X)[(size_t)gr * 32 + q];
        ushort4 o;
        o.x = bf16rne(v.x); o.y = bf16rne(v.y);
        o.z = bf16rne(v.z); o.w = bf16rne(v.w);
        *(ushort4*)&sA[r * 136 + q * 4] = o;
    }
    for (int i = tid; i < 128 * 16; i += 256) {
        int nr = i >> 4, q = i & 15;
        *(uint4*)&sB[nr * 136 + q * 8] = ((const uint4*)Wt)[i];
    }
    __syncthreads();

    const int wave = tid >> 6, lane = tid & 63;
    const int m = lane & 15, quad = lane >> 4;

    float4v acc[8];
#pragma unroll
    for (int t = 0; t < 8; t++) acc[t] = (float4v){0.f, 0.f, 0.f, 0.f};

    const unsigned short* pa = &sA[(wave * 16 + m) * 136 + quad * 8];
#pragma unroll
    for (int kc = 0; kc < 4; kc++) {
        short8 a = *(const short8*)(pa + kc * 32);
#pragma unroll
        for (int t = 0; t < 8; t++) {
            short8 b = *(const short8*)&sB[(t * 16 + m) * 136 + kc * 32 + quad * 8];
            acc[t] = __builtin_amdgcn_mfma_f32_16x16x32_bf16(a, b, acc[t], 0, 0, 0);
        }
    }
    // epilogue: scale row by dinv, store bf16. C/D: col=lane&15, row=quad*4+reg
    float dv[4];
#pragma unroll
    for (int r = 0; r < 4; r++) {
        int gr = row0 + wave * 16 + quad * 4 + r;
        dv[r] = (gr < n) ? dinv[gr] : 0.f;
    }
#pragma unroll
    for (int t = 0; t < 8; t++) {
#pragma unroll
        for (int r = 0; r < 4; r++) {
            int gr = row0 + wave * 16 + quad * 4 + r;
            if (gr < n) Yb[(size_t)gr * 128 + t * 16 + m] = bf16rne(acc[t][r] * dv[r]);
        }
    }
}

// -------- CSR gather: h = relu( dinv[c]*(T[c] + sum ew*T[r]) + bias ) ------
// 32 lanes per node, each lane owns 4 cols (uint2 = 4 bf16 per edge row).
__global__ __launch_bounds__(256) void gather_csr(const uint2* __restrict__ cursor2,
                                                  const uint2* __restrict__ sedge,
                                                  const unsigned short* __restrict__ xwb,
                                                  const float* __restrict__ dinv,
                                                  const float* __restrict__ bias,
                                                  float* __restrict__ h) {
    int node = blockIdx.x * 8 + (threadIdx.x >> 5);
    int lane = threadIdx.x & 31;
    if (node >= N_NODES) return;
    uint2 cu = cursor2[node];
    int start = (int)cu.x, end = (int)cu.y;
    const uint2* tab = (const uint2*)xwb;   // 32 uint2 per node row

    uint2 q0 = tab[(size_t)node * 32 + lane];
    float4 acc;
    acc.x = __uint_as_float(q0.x << 16);
    acc.y = __uint_as_float(q0.x & 0xFFFF0000u);
    acc.z = __uint_as_float(q0.y << 16);
    acc.w = __uint_as_float(q0.y & 0xFFFF0000u);

    int e = start;
    for (; e + 4 <= end; e += 4) {
        uint2 E[4]; uint2 q[4];
#pragma unroll
        for (int j = 0; j < 4; j++) E[j] = sedge[e + j];
#pragma unroll
        for (int j = 0; j < 4; j++) q[j] = tab[(size_t)E[j].x * 32 + lane];
#pragma unroll
        for (int j = 0; j < 4; j++) {
            float w = __uint_as_float(E[j].y);
            acc.x += w * __uint_as_float(q[j].x << 16);
            acc.y += w * __uint_as_float(q[j].x & 0xFFFF0000u);
            acc.z += w * __uint_as_float(q[j].y << 16);
            acc.w += w * __uint_as_float(q[j].y & 0xFFFF0000u);
        }
    }
    for (; e < end; ++e) {
        uint2 E = sedge[e];
        float w = __uint_as_float(E.y);
        uint2 q = tab[(size_t)E.x * 32 + lane];
        acc.x += w * __uint_as_float(q.x << 16);
        acc.y += w * __uint_as_float(q.x & 0xFFFF0000u);
        acc.z += w * __uint_as_float(q.y << 16);
        acc.w += w * __uint_as_float(q.y & 0xFFFF0000u);
    }

    float d = dinv[node];
    float4 bb = ((const float4*)bias)[lane];
    acc.x = fmaxf(fmaf(d, acc.x, bb.x), 0.f);
    acc.y = fmaxf(fmaf(d, acc.y, bb.y), 0.f);
    acc.z = fmaxf(fmaf(d, acc.z, bb.z), 0.f);
    acc.w = fmaxf(fmaf(d, acc.w, bb.w), 0.f);
    ((float4*)h)[(size_t)node * 32 + lane] = acc;
}

// ------------- final: out[n] = h[n] . lin_w + lin_b ------------------------
__global__ __launch_bounds__(256) void final_dot(const float* __restrict__ h,
                                                 const float* __restrict__ lw,
                                                 const float* __restrict__ lb,
                                                 float* __restrict__ out) {
    int node = blockIdx.x * 4 + (threadIdx.x >> 6);
    int lane = threadIdx.x & 63;
    if (node >= N_NODES) return;
    float2 hv = ((const float2*)h)[node * 64 + lane];
    float2 wv = ((const float2*)lw)[lane];
    float p = hv.x * wv.x + hv.y * wv.y;
#pragma unroll
    for (int off = 32; off; off >>= 1) p += __shfl_down(p, off);
    if (lane == 0) out[node] = p + lb[0];
}

extern "C" void kernel_launch(void* const* d_in, const int* in_sizes, int n_in,
                              void* d_out, int out_size, void* d_ws, size_t ws_size,
                              hipStream_t stream) {
    const float* x   = (const float*)d_in[0];
    const int*   ei  = (const int*)d_in[1];   // int64 in reference -> int32 on device
    const float* ea  = (const float*)d_in[2];
    const float* W1  = (const float*)d_in[3];
    const float* b1  = (const float*)d_in[4];
    const float* W2  = (const float*)d_in[5];
    const float* b2  = (const float*)d_in[6];
    const float* W3  = (const float*)d_in[7];
    const float* b3  = (const float*)d_in[8];
    const float* lw  = (const float*)d_in[9];
    const float* lb  = (const float*)d_in[10];
    float*       out = (float*)d_out;

    const int* row = ei;        // edge_index[0]
    const int* col = ei + NE;   // edge_index[1]

    const int BS = 256;
    int gBinA   = (NE + EPB - 1) / EPB;
    int gFinal  = (N_NODES + 3) / 4;
    int gGather = (N_NODES + 7) / 8;
    int gGemm   = (N_NODES + 63) / 64;

    // workspace layout (~110 MB), 8B-aligned blocks first:
    //   babuf uint2[NB*BCAP] | sedge uint2[NB*BCAP] | cursor2 uint2[N] |
    //   dinv f[N] | gbcur i[128] | Wt u16[16384] | xwb u16[N*C] | h f[N*C]
    char* wsb = (char*)d_ws;
    uint2*          babuf   = (uint2*)wsb;          wsb += (size_t)NB * BCAP * 8;
    uint2*          sedge   = (uint2*)wsb;          wsb += (size_t)NB * BCAP * 8;
    uint2*          cursor2 = (uint2*)wsb;          wsb += (size_t)N_NODES * 8;
    float*          dinv    = (float*)wsb;          wsb += (size_t)N_NODES * 4;
    int*            gbcur   = (int*)wsb;            wsb += 128 * 4;
    unsigned short* Wt      = (unsigned short*)wsb; wsb += 16384 * 2;
    unsigned short* xwb     = (unsigned short*)wsb; wsb += (size_t)N_NODES * C * 2;
    float*          hbuf    = (float*)wsb;

    hipMemsetAsync(gbcur, 0, 128 * 4, stream);
    binA_kernel<<<gBinA, BS, 0, stream>>>(row, col, ea, gbcur, babuf);
    binB_kernel<<<NB, BS, 0, stream>>>(gbcur, babuf, dinv, cursor2, sedge);

    // layer 1
    wt_kernel<<<64, BS, 0, stream>>>(W1, Wt);
    gemm_mfma<<<gGemm, BS, 0, stream>>>(x, Wt, dinv, xwb, N_NODES);
    gather_csr<<<gGather, BS, 0, stream>>>(cursor2, sedge, xwb, dinv, b1, hbuf);
    // layer 2
    wt_kernel<<<64, BS, 0, stream>>>(W2, Wt);
    gemm_mfma<<<gGemm, BS, 0, stream>>>(hbuf, Wt, dinv, xwb, N_NODES);
    gather_csr<<<gGather, BS, 0, stream>>>(cursor2, sedge, xwb, dinv, b2, hbuf);
    // layer 3
    wt_kernel<<<64, BS, 0, stream>>>(W3, Wt);
    gemm_mfma<<<gGemm, BS, 0, stream>>>(hbuf, Wt, dinv, xwb, N_NODES);
    gather_csr<<<gGather, BS, 0, stream>>>(cursor2, sedge, xwb, dinv, b3, hbuf);

    final_dot<<<gFinal, BS, 0, stream>>>(hbuf, lw, lb, out);
}

// Round 9
// 446.442 us; speedup vs baseline: 28.4721x; 1.1027x over previous
//
#include <hip/hip_runtime.h>

#define N_NODES 100000
#define NE      1600000
#define C       128
#define NB      98        // buckets of 1024 destination nodes
#define BCAP    20480     // per-bucket capacity; mean 16384, ~32-sigma margin
#define EPB     2048      // edges per binA block

typedef __attribute__((ext_vector_type(8))) short short8;
typedef __attribute__((ext_vector_type(4))) float float4v;

__device__ __forceinline__ unsigned short bf16rne(float f) {
    unsigned int u = __float_as_uint(f);
    return (unsigned short)((u + 0x7FFFu + ((u >> 16) & 1u)) >> 16);
}
__device__ __forceinline__ float blo(unsigned int u) { return __uint_as_float(u << 16); }
__device__ __forceinline__ float bhi(unsigned int u) { return __uint_as_float(u & 0xFFFF0000u); }

// ---- binA: coarse-bucket edges by c>>10, block-aggregated appends ---------
// record = { (c_low<<17) | r , ew_bits }
__global__ __launch_bounds__(256) void binA_kernel(const int* __restrict__ row,
                                                   const int* __restrict__ col,
                                                   const float* __restrict__ ew,
                                                   int* __restrict__ gbcur,
                                                   uint2* __restrict__ babuf) {
    __shared__ int hcnt[NB];
    __shared__ int hofs[NB];
    __shared__ int hbase[NB];
    const int t = threadIdx.x;
    for (int i = t; i < NB; i += 256) { hcnt[i] = 0; hofs[i] = 0; }
    __syncthreads();

    const int e0 = blockIdx.x * EPB;
    int cc[8], rr[8]; float ee[8];
#pragma unroll
    for (int i = 0; i < 8; i++) {
        int e = e0 + i * 256 + t;
        if (e < NE) { cc[i] = col[e]; rr[i] = row[e]; ee[i] = ew[e]; }
        else cc[i] = -1;
    }
#pragma unroll
    for (int i = 0; i < 8; i++)
        if (cc[i] >= 0) atomicAdd(&hcnt[cc[i] >> 10], 1);
    __syncthreads();
    if (t < NB && hcnt[t] > 0) hbase[t] = atomicAdd(&gbcur[t], hcnt[t]);
    __syncthreads();
#pragma unroll
    for (int i = 0; i < 8; i++) {
        if (cc[i] < 0) continue;
        int b = cc[i] >> 10;
        int pos = hbase[b] + atomicAdd(&hofs[b], 1);
        if (pos < BCAP) {
            unsigned int meta = ((unsigned int)(cc[i] & 1023) << 17) | (unsigned int)rr[i];
            babuf[(size_t)b * BCAP + pos] = make_uint2(meta, __float_as_uint(ee[i]));
        }
    }
}

// ---- binB: per-bucket histogram + weighted degree + scan + local scatter --
__global__ __launch_bounds__(256) void binB_kernel(const int* __restrict__ gbcur,
                                                   const uint2* __restrict__ babuf,
                                                   float* __restrict__ dinv,
                                                   uint2* __restrict__ cursor2,
                                                   uint2* __restrict__ sedge) {
    __shared__ int   cnt[1024];
    __shared__ float deg[1024];
    __shared__ int   ofs[1024];
    __shared__ int   tsum[256];
    const int b = blockIdx.x, t = threadIdx.x;
    const int n0 = b << 10;
    const int nn = min(1024, N_NODES - n0);

    for (int i = t; i < 1024; i += 256) { cnt[i] = 0; deg[i] = 0.f; }
    __syncthreads();

    const int msize = min(gbcur[b], BCAP);
    const uint2* bb = babuf + (size_t)b * BCAP;
    for (int i = t; i < msize; i += 256) {
        uint2 m = bb[i];
        int cl = m.x >> 17;
        atomicAdd(&cnt[cl], 1);
        atomicAdd(&deg[cl], __uint_as_float(m.y));
    }
    __syncthreads();

    for (int i = t; i < nn; i += 256)
        dinv[n0 + i] = 1.0f / sqrtf(deg[i] + 1.0f);

    const int b4 = t * 4;
    int c0 = cnt[b4], c1 = cnt[b4 + 1], c2 = cnt[b4 + 2], c3 = cnt[b4 + 3];
    tsum[t] = c0 + c1 + c2 + c3;
    __syncthreads();
    for (int off = 1; off < 256; off <<= 1) {
        int v = (t >= off) ? tsum[t - off] : 0;
        __syncthreads();
        tsum[t] += v;
        __syncthreads();
    }
    int texcl = t ? tsum[t - 1] : 0;
    ofs[b4]     = texcl;
    ofs[b4 + 1] = texcl + c0;
    ofs[b4 + 2] = texcl + c0 + c1;
    ofs[b4 + 3] = texcl + c0 + c1 + c2;
    __syncthreads();

    const unsigned int ebase = (unsigned int)b * BCAP;
    for (int i = t; i < nn; i += 256) {
        unsigned int st = ebase + (unsigned int)ofs[i];
        cursor2[n0 + i] = make_uint2(st, st + (unsigned int)cnt[i]);
    }
    __syncthreads();

    for (int i = t; i < msize; i += 256) {
        uint2 m = bb[i];
        int cl = m.x >> 17;
        int p = atomicAdd(&ofs[cl], 1);
        sedge[(size_t)b * BCAP + p] = make_uint2(m.x & 0x1FFFFu, m.y);
    }
}

// ---- Wt[n][k] = bf16(W[k][n]) ---------------------------------------------
__global__ __launch_bounds__(256) void wt_kernel(const float* __restrict__ W,
                                                 unsigned short* __restrict__ Wt) {
    int i = blockIdx.x * 256 + threadIdx.x;
    int n = i >> 7, k = i & 127;
    Wt[i] = bf16rne(W[k * 128 + n]);
}

// ---------------- MFMA GEMM: T[n][128] = bf16( dinv[n] * (X @ W) ) ---------
// Input either fp32 (Xf, layer 1) or bf16 (Xb, layers 2/3).
__global__ __launch_bounds__(256) void gemm_mfma(const float* __restrict__ Xf,
                                                 const unsigned short* __restrict__ Xb,
                                                 const unsigned short* __restrict__ Wt,
                                                 const float* __restrict__ dinv,
                                                 unsigned short* __restrict__ Yb,
                                                 int n) {
    __shared__ unsigned short sA[64 * 136];   // [m][k]
    __shared__ unsigned short sB[128 * 136];  // [n][k]
    const int row0 = blockIdx.x * 64;
    const int tid  = threadIdx.x;

    if (Xf) {
        for (int i = tid; i < 64 * 32; i += 256) {
            int r = i >> 5, q = i & 31;
            int gr = row0 + r;
            float4 v = make_float4(0.f, 0.f, 0.f, 0.f);
            if (gr < n) v = ((const float4*)Xf)[(size_t)gr * 32 + q];
            ushort4 o;
            o.x = bf16rne(v.x); o.y = bf16rne(v.y);
            o.z = bf16rne(v.z); o.w = bf16rne(v.w);
            *(ushort4*)&sA[r * 136 + q * 4] = o;
        }
    } else {
        for (int i = tid; i < 64 * 16; i += 256) {
            int r = i >> 4, q = i & 15;
            int gr = row0 + r;
            uint4 v = make_uint4(0u, 0u, 0u, 0u);
            if (gr < n) v = ((const uint4*)Xb)[(size_t)gr * 16 + q];
            *(uint4*)&sA[r * 136 + q * 8] = v;
        }
    }
    for (int i = tid; i < 128 * 16; i += 256) {
        int nr = i >> 4, q = i & 15;
        *(uint4*)&sB[nr * 136 + q * 8] = ((const uint4*)Wt)[i];
    }
    __syncthreads();

    const int wave = tid >> 6, lane = tid & 63;
    const int m = lane & 15, quad = lane >> 4;

    float4v acc[8];
#pragma unroll
    for (int t = 0; t < 8; t++) acc[t] = (float4v){0.f, 0.f, 0.f, 0.f};

    const unsigned short* pa = &sA[(wave * 16 + m) * 136 + quad * 8];
#pragma unroll
    for (int kc = 0; kc < 4; kc++) {
        short8 a = *(const short8*)(pa + kc * 32);
#pragma unroll
        for (int t = 0; t < 8; t++) {
            short8 b = *(const short8*)&sB[(t * 16 + m) * 136 + kc * 32 + quad * 8];
            acc[t] = __builtin_amdgcn_mfma_f32_16x16x32_bf16(a, b, acc[t], 0, 0, 0);
        }
    }
    float dv[4];
#pragma unroll
    for (int r = 0; r < 4; r++) {
        int gr = row0 + wave * 16 + quad * 4 + r;
        dv[r] = (gr < n) ? dinv[gr] : 0.f;
    }
#pragma unroll
    for (int t = 0; t < 8; t++) {
#pragma unroll
        for (int r = 0; r < 4; r++) {
            int gr = row0 + wave * 16 + quad * 4 + r;
            if (gr < n) Yb[(size_t)gr * 128 + t * 16 + m] = bf16rne(acc[t][r] * dv[r]);
        }
    }
}

// -------- CSR gather: h = relu( dinv[c]*(T[c] + sum ew*T[r]) + bias ) ------
// 16 lanes per node (16 nodes/block), 16B dwordx4 per lane per edge.
// If outp != nullptr: fuse final linear (dot with lw, +lb) instead of h.
__global__ __launch_bounds__(256) void gather_csr(const uint2* __restrict__ cursor2,
                                                  const uint2* __restrict__ sedge,
                                                  const unsigned short* __restrict__ xwb,
                                                  const float* __restrict__ dinv,
                                                  const float* __restrict__ bias,
                                                  unsigned short* __restrict__ hb,
                                                  float* __restrict__ outp,
                                                  const float* __restrict__ lw,
                                                  const float* __restrict__ lb) {
    int node = blockIdx.x * 16 + (threadIdx.x >> 4);
    int lane = threadIdx.x & 15;
    if (node >= N_NODES) return;
    uint2 cu = cursor2[node];
    int e = (int)cu.x, end = (int)cu.y;
    const uint4* tab = (const uint4*)xwb;   // 16 uint4 per node row

    uint4 q0 = tab[(size_t)node * 16 + lane];
    float4 aL, aH;
    aL.x = blo(q0.x); aL.y = bhi(q0.x); aL.z = blo(q0.y); aL.w = bhi(q0.y);
    aH.x = blo(q0.z); aH.y = bhi(q0.z); aH.z = blo(q0.w); aH.w = bhi(q0.w);

    for (; e + 4 <= end; e += 4) {
        uint2 E[4]; uint4 q[4];
#pragma unroll
        for (int j = 0; j < 4; j++) E[j] = sedge[e + j];
#pragma unroll
        for (int j = 0; j < 4; j++) q[j] = tab[(size_t)E[j].x * 16 + lane];
#pragma unroll
        for (int j = 0; j < 4; j++) {
            float w = __uint_as_float(E[j].y);
            aL.x += w * blo(q[j].x); aL.y += w * bhi(q[j].x);
            aL.z += w * blo(q[j].y); aL.w += w * bhi(q[j].y);
            aH.x += w * blo(q[j].z); aH.y += w * bhi(q[j].z);
            aH.z += w * blo(q[j].w); aH.w += w * bhi(q[j].w);
        }
    }
    for (; e < end; ++e) {
        uint2 E = sedge[e];
        float w = __uint_as_float(E.y);
        uint4 q = tab[(size_t)E.x * 16 + lane];
        aL.x += w * blo(q.x); aL.y += w * bhi(q.x);
        aL.z += w * blo(q.y); aL.w += w * bhi(q.y);
        aH.x += w * blo(q.z); aH.y += w * bhi(q.z);
        aH.z += w * blo(q.w); aH.w += w * bhi(q.w);
    }

    float d = dinv[node];
    float4 b0 = ((const float4*)bias)[lane * 2];
    float4 b1 = ((const float4*)bias)[lane * 2 + 1];
    aL.x = fmaxf(fmaf(d, aL.x, b0.x), 0.f);
    aL.y = fmaxf(fmaf(d, aL.y, b0.y), 0.f);
    aL.z = fmaxf(fmaf(d, aL.z, b0.z), 0.f);
    aL.w = fmaxf(fmaf(d, aL.w, b0.w), 0.f);
    aH.x = fmaxf(fmaf(d, aH.x, b1.x), 0.f);
    aH.y = fmaxf(fmaf(d, aH.y, b1.y), 0.f);
    aH.z = fmaxf(fmaf(d, aH.z, b1.z), 0.f);
    aH.w = fmaxf(fmaf(d, aH.w, b1.w), 0.f);

    if (outp) {
        float4 w0 = ((const float4*)lw)[lane * 2];
        float4 w1 = ((const float4*)lw)[lane * 2 + 1];
        float p = aL.x * w0.x + aL.y * w0.y + aL.z * w0.z + aL.w * w0.w +
                  aH.x * w1.x + aH.y * w1.y + aH.z * w1.z + aH.w * w1.w;
#pragma unroll
        for (int off = 8; off; off >>= 1) p += __shfl_down(p, off);
        if (lane == 0) outp[node] = p + lb[0];
    } else {
        uint4 o;
        o.x = (unsigned int)bf16rne(aL.x) | ((unsigned int)bf16rne(aL.y) << 16);
        o.y = (unsigned int)bf16rne(aL.z) | ((unsigned int)bf16rne(aL.w) << 16);
        o.z = (unsigned int)bf16rne(aH.x) | ((unsigned int)bf16rne(aH.y) << 16);
        o.w = (unsigned int)bf16rne(aH.z) | ((unsigned int)bf16rne(aH.w) << 16);
        ((uint4*)hb)[(size_t)node * 16 + lane] = o;
    }
}

extern "C" void kernel_launch(void* const* d_in, const int* in_sizes, int n_in,
                              void* d_out, int out_size, void* d_ws, size_t ws_size,
                              hipStream_t stream) {
    const float* x   = (const float*)d_in[0];
    const int*   ei  = (const int*)d_in[1];   // int64 in reference -> int32 on device
    const float* ea  = (const float*)d_in[2];
    const float* W1  = (const float*)d_in[3];
    const float* b1  = (const float*)d_in[4];
    const float* W2  = (const float*)d_in[5];
    const float* b2  = (const float*)d_in[6];
    const float* W3  = (const float*)d_in[7];
    const float* b3  = (const float*)d_in[8];
    const float* lw  = (const float*)d_in[9];
    const float* lb  = (const float*)d_in[10];
    float*       out = (float*)d_out;

    const int* row = ei;        // edge_index[0]
    const int* col = ei + NE;   // edge_index[1]

    const int BS = 256;
    int gBinA   = (NE + EPB - 1) / EPB;
    int gGather = (N_NODES + 15) / 16;
    int gGemm   = (N_NODES + 63) / 64;

    // workspace layout (~85 MB), 8B-aligned blocks first:
    //   babuf uint2[NB*BCAP] | sedge uint2[NB*BCAP] | cursor2 uint2[N] |
    //   dinv f[N] | gbcur i[128] | Wt u16[16384] | xwb u16[N*C] | hb u16[N*C]
    char* wsb = (char*)d_ws;
    uint2*          babuf   = (uint2*)wsb;          wsb += (size_t)NB * BCAP * 8;
    uint2*          sedge   = (uint2*)wsb;          wsb += (size_t)NB * BCAP * 8;
    uint2*          cursor2 = (uint2*)wsb;          wsb += (size_t)N_NODES * 8;
    float*          dinv    = (float*)wsb;          wsb += (size_t)N_NODES * 4;
    int*            gbcur   = (int*)wsb;            wsb += 128 * 4;
    unsigned short* Wt      = (unsigned short*)wsb; wsb += 16384 * 2;
    unsigned short* xwb     = (unsigned short*)wsb; wsb += (size_t)N_NODES * C * 2;
    unsigned short* hb      = (unsigned short*)wsb;

    hipMemsetAsync(gbcur, 0, 128 * 4, stream);
    binA_kernel<<<gBinA, BS, 0, stream>>>(row, col, ea, gbcur, babuf);
    binB_kernel<<<NB, BS, 0, stream>>>(gbcur, babuf, dinv, cursor2, sedge);

    // layer 1 (fp32 input)
    wt_kernel<<<64, BS, 0, stream>>>(W1, Wt);
    gemm_mfma<<<gGemm, BS, 0, stream>>>(x, nullptr, Wt, dinv, xwb, N_NODES);
    gather_csr<<<gGather, BS, 0, stream>>>(cursor2, sedge, xwb, dinv, b1, hb,
                                           nullptr, nullptr, nullptr);
    // layer 2 (bf16 h input)
    wt_kernel<<<64, BS, 0, stream>>>(W2, Wt);
    gemm_mfma<<<gGemm, BS, 0, stream>>>(nullptr, hb, Wt, dinv, xwb, N_NODES);
    gather_csr<<<gGather, BS, 0, stream>>>(cursor2, sedge, xwb, dinv, b2, hb,
                                           nullptr, nullptr, nullptr);
    // layer 3 + fused final linear
    wt_kernel<<<64, BS, 0, stream>>>(W3, Wt);
    gemm_mfma<<<gGemm, BS, 0, stream>>>(nullptr, hb, Wt, dinv, xwb, N_NODES);
    gather_csr<<<gGather, BS, 0, stream>>>(cursor2, sedge, xwb, dinv, b3, nullptr,
                                           out, lw, lb);
}

// Round 10
// 440.155 us; speedup vs baseline: 28.8789x; 1.0143x over previous
//
#include <hip/hip_runtime.h>

#define N_NODES 100000
#define NE      1600000
#define C       128
#define NB      98        // buckets of 1024 destination nodes
#define BCAP    20480     // per-bucket capacity; mean 16384, ~32-sigma margin
#define EPB     2048      // edges per binA block

typedef __attribute__((ext_vector_type(8))) short short8;
typedef __attribute__((ext_vector_type(4))) float float4v;

__device__ __forceinline__ unsigned short bf16rne(float f) {
    unsigned int u = __float_as_uint(f);
    return (unsigned short)((u + 0x7FFFu + ((u >> 16) & 1u)) >> 16);
}
__device__ __forceinline__ float blo(unsigned int u) { return __uint_as_float(u << 16); }
__device__ __forceinline__ float bhi(unsigned int u) { return __uint_as_float(u & 0xFFFF0000u); }

// ---- binA v2: coarse-bucket by c>>10 with LDS-staged COALESCED writes -----
// Local bucket-sort of the block's 2048 records in LDS, then sequential
// write-out: consecutive lanes -> consecutive global addresses per run.
// record = { (c_low<<17) | r , ew_bits }
__global__ __launch_bounds__(256) void binA_kernel(const int* __restrict__ row,
                                                   const int* __restrict__ col,
                                                   const float* __restrict__ ew,
                                                   int* __restrict__ gbcur,
                                                   uint2* __restrict__ babuf) {
    __shared__ int   hcnt[NB];
    __shared__ int   hofs[NB];
    __shared__ int   hbase[NB];
    __shared__ int   lofs[NB];
    __shared__ uint2 recs[EPB];   // 16 KB
    __shared__ int   gdst[EPB];   // 8 KB
    const int t = threadIdx.x;
    for (int i = t; i < NB; i += 256) { hcnt[i] = 0; hofs[i] = 0; }
    __syncthreads();

    const int e0 = blockIdx.x * EPB;
    int cc[8], rr[8]; float ee[8];
#pragma unroll
    for (int i = 0; i < 8; i++) {
        int e = e0 + i * 256 + t;
        if (e < NE) { cc[i] = col[e]; rr[i] = row[e]; ee[i] = ew[e]; }
        else cc[i] = -1;
    }
#pragma unroll
    for (int i = 0; i < 8; i++)
        if (cc[i] >= 0) atomicAdd(&hcnt[cc[i] >> 10], 1);
    __syncthreads();
    if (t < NB) {
        int c = hcnt[t];
        hbase[t] = c ? atomicAdd(&gbcur[t], c) : 0;
    }
    if (t == 0) {
        int run = 0;
        for (int b = 0; b < NB; b++) { lofs[b] = run; run += hcnt[b]; }
    }
    __syncthreads();
#pragma unroll
    for (int i = 0; i < 8; i++) {
        if (cc[i] < 0) continue;
        int b = cc[i] >> 10;
        int lpos = atomicAdd(&hofs[b], 1);
        int si = lofs[b] + lpos;
        unsigned int meta = ((unsigned int)(cc[i] & 1023) << 17) | (unsigned int)rr[i];
        recs[si] = make_uint2(meta, __float_as_uint(ee[i]));
        int gp = hbase[b] + lpos;
        gdst[si] = (gp < BCAP) ? (b * BCAP + gp) : -1;
    }
    __syncthreads();
    const int valid = lofs[NB - 1] + hcnt[NB - 1];
    for (int i = t; i < valid; i += 256) {
        int g = gdst[i];
        if (g >= 0) babuf[g] = recs[i];
    }
}

// ---- binB: per-bucket histogram + weighted degree + scan + local scatter --
__global__ __launch_bounds__(256) void binB_kernel(const int* __restrict__ gbcur,
                                                   const uint2* __restrict__ babuf,
                                                   float* __restrict__ dinv,
                                                   uint2* __restrict__ cursor2,
                                                   uint2* __restrict__ sedge) {
    __shared__ int   cnt[1024];
    __shared__ float deg[1024];
    __shared__ int   ofs[1024];
    __shared__ int   tsum[256];
    const int b = blockIdx.x, t = threadIdx.x;
    const int n0 = b << 10;
    const int nn = min(1024, N_NODES - n0);

    for (int i = t; i < 1024; i += 256) { cnt[i] = 0; deg[i] = 0.f; }
    __syncthreads();

    const int msize = min(gbcur[b], BCAP);
    const uint2* bb = babuf + (size_t)b * BCAP;
    for (int i = t; i < msize; i += 256) {
        uint2 m = bb[i];
        int cl = m.x >> 17;
        atomicAdd(&cnt[cl], 1);
        atomicAdd(&deg[cl], __uint_as_float(m.y));
    }
    __syncthreads();

    for (int i = t; i < nn; i += 256)
        dinv[n0 + i] = 1.0f / sqrtf(deg[i] + 1.0f);

    const int b4 = t * 4;
    int c0 = cnt[b4], c1 = cnt[b4 + 1], c2 = cnt[b4 + 2], c3 = cnt[b4 + 3];
    tsum[t] = c0 + c1 + c2 + c3;
    __syncthreads();
    for (int off = 1; off < 256; off <<= 1) {
        int v = (t >= off) ? tsum[t - off] : 0;
        __syncthreads();
        tsum[t] += v;
        __syncthreads();
    }
    int texcl = t ? tsum[t - 1] : 0;
    ofs[b4]     = texcl;
    ofs[b4 + 1] = texcl + c0;
    ofs[b4 + 2] = texcl + c0 + c1;
    ofs[b4 + 3] = texcl + c0 + c1 + c2;
    __syncthreads();

    const unsigned int ebase = (unsigned int)b * BCAP;
    for (int i = t; i < nn; i += 256) {
        unsigned int st = ebase + (unsigned int)ofs[i];
        cursor2[n0 + i] = make_uint2(st, st + (unsigned int)cnt[i]);
    }
    __syncthreads();

    for (int i = t; i < msize; i += 256) {
        uint2 m = bb[i];
        int cl = m.x >> 17;
        int p = atomicAdd(&ofs[cl], 1);
        sedge[(size_t)b * BCAP + p] = make_uint2(m.x & 0x1FFFFu, m.y);
    }
}

// ---- Wt[l][n][k] = bf16(Wl[k][n]) for all 3 layers in one dispatch --------
__global__ __launch_bounds__(256) void wt3_kernel(const float* __restrict__ W1,
                                                  const float* __restrict__ W2,
                                                  const float* __restrict__ W3,
                                                  unsigned short* __restrict__ Wt) {
    int layer = blockIdx.y;
    const float* W = layer == 0 ? W1 : (layer == 1 ? W2 : W3);
    int i = blockIdx.x * 256 + threadIdx.x;   // 16384 per layer
    int n = i >> 7, k = i & 127;
    Wt[layer * 16384 + i] = bf16rne(W[k * 128 + n]);
}

// ---------------- MFMA GEMM: T[n][128] = bf16( dinv[n] * (X @ W) ) ---------
// Input either fp32 (Xf, layer 1) or bf16 (Xb, layers 2/3).
__global__ __launch_bounds__(256) void gemm_mfma(const float* __restrict__ Xf,
                                                 const unsigned short* __restrict__ Xb,
                                                 const unsigned short* __restrict__ Wt,
                                                 const float* __restrict__ dinv,
                                                 unsigned short* __restrict__ Yb,
                                                 int n) {
    __shared__ unsigned short sA[64 * 136];   // [m][k]
    __shared__ unsigned short sB[128 * 136];  // [n][k]
    const int row0 = blockIdx.x * 64;
    const int tid  = threadIdx.x;

    if (Xf) {
        for (int i = tid; i < 64 * 32; i += 256) {
            int r = i >> 5, q = i & 31;
            int gr = row0 + r;
            float4 v = make_float4(0.f, 0.f, 0.f, 0.f);
            if (gr < n) v = ((const float4*)Xf)[(size_t)gr * 32 + q];
            ushort4 o;
            o.x = bf16rne(v.x); o.y = bf16rne(v.y);
            o.z = bf16rne(v.z); o.w = bf16rne(v.w);
            *(ushort4*)&sA[r * 136 + q * 4] = o;
        }
    } else {
        for (int i = tid; i < 64 * 16; i += 256) {
            int r = i >> 4, q = i & 15;
            int gr = row0 + r;
            uint4 v = make_uint4(0u, 0u, 0u, 0u);
            if (gr < n) v = ((const uint4*)Xb)[(size_t)gr * 16 + q];
            *(uint4*)&sA[r * 136 + q * 8] = v;
        }
    }
    for (int i = tid; i < 128 * 16; i += 256) {
        int nr = i >> 4, q = i & 15;
        *(uint4*)&sB[nr * 136 + q * 8] = ((const uint4*)Wt)[i];
    }
    __syncthreads();

    const int wave = tid >> 6, lane = tid & 63;
    const int m = lane & 15, quad = lane >> 4;

    float4v acc[8];
#pragma unroll
    for (int t = 0; t < 8; t++) acc[t] = (float4v){0.f, 0.f, 0.f, 0.f};

    const unsigned short* pa = &sA[(wave * 16 + m) * 136 + quad * 8];
#pragma unroll
    for (int kc = 0; kc < 4; kc++) {
        short8 a = *(const short8*)(pa + kc * 32);
#pragma unroll
        for (int t = 0; t < 8; t++) {
            short8 b = *(const short8*)&sB[(t * 16 + m) * 136 + kc * 32 + quad * 8];
            acc[t] = __builtin_amdgcn_mfma_f32_16x16x32_bf16(a, b, acc[t], 0, 0, 0);
        }
    }
    float dv[4];
#pragma unroll
    for (int r = 0; r < 4; r++) {
        int gr = row0 + wave * 16 + quad * 4 + r;
        dv[r] = (gr < n) ? dinv[gr] : 0.f;
    }
#pragma unroll
    for (int t = 0; t < 8; t++) {
#pragma unroll
        for (int r = 0; r < 4; r++) {
            int gr = row0 + wave * 16 + quad * 4 + r;
            if (gr < n) Yb[(size_t)gr * 128 + t * 16 + m] = bf16rne(acc[t][r] * dv[r]);
        }
    }
}

// -------- CSR gather: h = relu( dinv[c]*(T[c] + sum ew*T[r]) + bias ) ------
// 16 lanes per node (16 nodes/block), 16B dwordx4 per lane per edge.
// If outp != nullptr: fuse final linear (dot with lw, +lb) instead of h.
__global__ __launch_bounds__(256) void gather_csr(const uint2* __restrict__ cursor2,
                                                  const uint2* __restrict__ sedge,
                                                  const unsigned short* __restrict__ xwb,
                                                  const float* __restrict__ dinv,
                                                  const float* __restrict__ bias,
                                                  unsigned short* __restrict__ hb,
                                                  float* __restrict__ outp,
                                                  const float* __restrict__ lw,
                                                  const float* __restrict__ lb) {
    int node = blockIdx.x * 16 + (threadIdx.x >> 4);
    int lane = threadIdx.x & 15;
    if (node >= N_NODES) return;
    uint2 cu = cursor2[node];
    int e = (int)cu.x, end = (int)cu.y;
    const uint4* tab = (const uint4*)xwb;   // 16 uint4 per node row

    uint4 q0 = tab[(size_t)node * 16 + lane];
    float4 aL, aH;
    aL.x = blo(q0.x); aL.y = bhi(q0.x); aL.z = blo(q0.y); aL.w = bhi(q0.y);
    aH.x = blo(q0.z); aH.y = bhi(q0.z); aH.z = blo(q0.w); aH.w = bhi(q0.w);

    for (; e + 4 <= end; e += 4) {
        uint2 E[4]; uint4 q[4];
#pragma unroll
        for (int j = 0; j < 4; j++) E[j] = sedge[e + j];
#pragma unroll
        for (int j = 0; j < 4; j++) q[j] = tab[(size_t)E[j].x * 16 + lane];
#pragma unroll
        for (int j = 0; j < 4; j++) {
            float w = __uint_as_float(E[j].y);
            aL.x += w * blo(q[j].x); aL.y += w * bhi(q[j].x);
            aL.z += w * blo(q[j].y); aL.w += w * bhi(q[j].y);
            aH.x += w * blo(q[j].z); aH.y += w * bhi(q[j].z);
            aH.z += w * blo(q[j].w); aH.w += w * bhi(q[j].w);
        }
    }
    for (; e < end; ++e) {
        uint2 E = sedge[e];
        float w = __uint_as_float(E.y);
        uint4 q = tab[(size_t)E.x * 16 + lane];
        aL.x += w * blo(q.x); aL.y += w * bhi(q.x);
        aL.z += w * blo(q.y); aL.w += w * bhi(q.y);
        aH.x += w * blo(q.z); aH.y += w * bhi(q.z);
        aH.z += w * blo(q.w); aH.w += w * bhi(q.w);
    }

    float d = dinv[node];
    float4 b0 = ((const float4*)bias)[lane * 2];
    float4 b1 = ((const float4*)bias)[lane * 2 + 1];
    aL.x = fmaxf(fmaf(d, aL.x, b0.x), 0.f);
    aL.y = fmaxf(fmaf(d, aL.y, b0.y), 0.f);
    aL.z = fmaxf(fmaf(d, aL.z, b0.z), 0.f);
    aL.w = fmaxf(fmaf(d, aL.w, b0.w), 0.f);
    aH.x = fmaxf(fmaf(d, aH.x, b1.x), 0.f);
    aH.y = fmaxf(fmaf(d, aH.y, b1.y), 0.f);
    aH.z = fmaxf(fmaf(d, aH.z, b1.z), 0.f);
    aH.w = fmaxf(fmaf(d, aH.w, b1.w), 0.f);

    if (outp) {
        float4 w0 = ((const float4*)lw)[lane * 2];
        float4 w1 = ((const float4*)lw)[lane * 2 + 1];
        float p = aL.x * w0.x + aL.y * w0.y + aL.z * w0.z + aL.w * w0.w +
                  aH.x * w1.x + aH.y * w1.y + aH.z * w1.z + aH.w * w1.w;
#pragma unroll
        for (int off = 8; off; off >>= 1) p += __shfl_down(p, off);
        if (lane == 0) outp[node] = p + lb[0];
    } else {
        uint4 o;
        o.x = (unsigned int)bf16rne(aL.x) | ((unsigned int)bf16rne(aL.y) << 16);
        o.y = (unsigned int)bf16rne(aL.z) | ((unsigned int)bf16rne(aL.w) << 16);
        o.z = (unsigned int)bf16rne(aH.x) | ((unsigned int)bf16rne(aH.y) << 16);
        o.w = (unsigned int)bf16rne(aH.z) | ((unsigned int)bf16rne(aH.w) << 16);
        ((uint4*)hb)[(size_t)node * 16 + lane] = o;
    }
}

extern "C" void kernel_launch(void* const* d_in, const int* in_sizes, int n_in,
                              void* d_out, int out_size, void* d_ws, size_t ws_size,
                              hipStream_t stream) {
    const float* x   = (const float*)d_in[0];
    const int*   ei  = (const int*)d_in[1];   // int64 in reference -> int32 on device
    const float* ea  = (const float*)d_in[2];
    const float* W1  = (const float*)d_in[3];
    const float* b1  = (const float*)d_in[4];
    const float* W2  = (const float*)d_in[5];
    const float* b2  = (const float*)d_in[6];
    const float* W3  = (const float*)d_in[7];
    const float* b3  = (const float*)d_in[8];
    const float* lw  = (const float*)d_in[9];
    const float* lb  = (const float*)d_in[10];
    float*       out = (float*)d_out;

    const int* row = ei;        // edge_index[0]
    const int* col = ei + NE;   // edge_index[1]

    const int BS = 256;
    int gBinA   = (NE + EPB - 1) / EPB;
    int gGather = (N_NODES + 15) / 16;
    int gGemm   = (N_NODES + 63) / 64;

    // workspace layout (~85 MB), 8B-aligned blocks first:
    //   babuf uint2[NB*BCAP] | sedge uint2[NB*BCAP] | cursor2 uint2[N] |
    //   dinv f[N] | gbcur i[128] | Wt u16[3*16384] | xwb u16[N*C] | hb u16[N*C]
    char* wsb = (char*)d_ws;
    uint2*          babuf   = (uint2*)wsb;          wsb += (size_t)NB * BCAP * 8;
    uint2*          sedge   = (uint2*)wsb;          wsb += (size_t)NB * BCAP * 8;
    uint2*          cursor2 = (uint2*)wsb;          wsb += (size_t)N_NODES * 8;
    float*          dinv    = (float*)wsb;          wsb += (size_t)N_NODES * 4;
    int*            gbcur   = (int*)wsb;            wsb += 128 * 4;
    unsigned short* Wt      = (unsigned short*)wsb; wsb += 3 * 16384 * 2;
    unsigned short* xwb     = (unsigned short*)wsb; wsb += (size_t)N_NODES * C * 2;
    unsigned short* hb      = (unsigned short*)wsb;

    hipMemsetAsync(gbcur, 0, 128 * 4, stream);
    wt3_kernel<<<dim3(64, 3), BS, 0, stream>>>(W1, W2, W3, Wt);
    binA_kernel<<<gBinA, BS, 0, stream>>>(row, col, ea, gbcur, babuf);
    binB_kernel<<<NB, BS, 0, stream>>>(gbcur, babuf, dinv, cursor2, sedge);

    // layer 1 (fp32 input)
    gemm_mfma<<<gGemm, BS, 0, stream>>>(x, nullptr, Wt, dinv, xwb, N_NODES);
    gather_csr<<<gGather, BS, 0, stream>>>(cursor2, sedge, xwb, dinv, b1, hb,
                                           nullptr, nullptr, nullptr);
    // layer 2 (bf16 h input)
    gemm_mfma<<<gGemm, BS, 0, stream>>>(nullptr, hb, Wt + 16384, dinv, xwb, N_NODES);
    gather_csr<<<gGather, BS, 0, stream>>>(cursor2, sedge, xwb, dinv, b2, hb,
                                           nullptr, nullptr, nullptr);
    // layer 3 + fused final linear
    gemm_mfma<<<gGemm, BS, 0, stream>>>(nullptr, hb, Wt + 32768, dinv, xwb, N_NODES);
    gather_csr<<<gGather, BS, 0, stream>>>(cursor2, sedge, xwb, dinv, b3, nullptr,
                                           out, lw, lb);
}